// Round 12
// baseline (803.053 us; speedup 1.0000x reference)
//
#include <hip/hip_runtime.h>
#include <hip/hip_bf16.h>

#define S_LEN 1024
#define E_DIM 512
#define INNER_D 1024
#define NHEAD 8
#define DHEAD 128

typedef unsigned short u16;
typedef unsigned int u32;
typedef __attribute__((ext_vector_type(8))) short short8;
typedef __attribute__((ext_vector_type(4))) float f32x4;

union S8 { short8 v; u16 u[8]; uint4 q; };

__device__ __forceinline__ u16 f2bf(float f) {
  u32 u = __float_as_uint(f);
  u32 r = u + 0x7FFFu + ((u >> 16) & 1u);
  return (u16)(r >> 16);
}
__device__ __forceinline__ float bf2f(u16 u) { return __uint_as_float(((u32)u) << 16); }

// ---------------- embedding ----------------
__global__ __launch_bounds__(128) void embed_kernel(
    const float* __restrict__ xe, const float* __restrict__ xm,
    const float* __restrict__ W, const float* __restrict__ bias,
    float* __restrict__ x)
{
  int row = blockIdx.x;
  int tid = threadIdx.x;
  __shared__ float in_s[25];
  if (tid < 21) in_s[tid] = xe[row * 21 + tid];
  else if (tid < 25) in_s[tid] = xm[row * 4 + tid - 21];
  __syncthreads();
#pragma unroll
  for (int rep = 0; rep < 4; rep++) {
    int e = tid + rep * 128;
    float acc = bias[e];
#pragma unroll
    for (int i = 0; i < 25; i++) acc += in_s[i] * W[i * E_DIM + e];
    x[(size_t)row * E_DIM + e] = acc;
  }
}

// ---------------- layernorm -> bf16 ----------------
__global__ __launch_bounds__(256) void ln_kernel(
    const float* __restrict__ x, const float* __restrict__ w, u16* __restrict__ out)
{
  int row = blockIdx.x, tid = threadIdx.x;
  const float* xr = x + (size_t)row * E_DIM;
  float2 v = *(const float2*)(xr + tid * 2);
  float s = v.x + v.y, q = v.x * v.x + v.y * v.y;
#pragma unroll
  for (int off = 32; off; off >>= 1) { s += __shfl_xor(s, off); q += __shfl_xor(q, off); }
  __shared__ float ssum[4], ssq[4];
  int wv = tid >> 6;
  if ((tid & 63) == 0) { ssum[wv] = s; ssq[wv] = q; }
  __syncthreads();
  s = ssum[0] + ssum[1] + ssum[2] + ssum[3];
  q = ssq[0] + ssq[1] + ssq[2] + ssq[3];
  float mu = s * (1.f / E_DIM);
  float var = q * (1.f / E_DIM) - mu * mu;
  float rs = rsqrtf(var + 1e-5f);
  int e = tid * 2;
  ushort2 o;
  o.x = f2bf((v.x - mu) * rs * w[e]);
  o.y = f2bf((v.y - mu) * rs * w[e + 1]);
  *(ushort2*)(out + (size_t)row * E_DIM + e) = o;
}

__global__ __launch_bounds__(256) void ln_final_kernel(
    const float* __restrict__ x, const float* __restrict__ w, float* __restrict__ out)
{
  int ridx = blockIdx.x;
  int b = ridx / 96, r = ridx % 96;
  int row = b * S_LEN + (S_LEN - 96) + r;
  int tid = threadIdx.x;
  const float* xr = x + (size_t)row * E_DIM;
  float2 v = *(const float2*)(xr + tid * 2);
  float s = v.x + v.y, q = v.x * v.x + v.y * v.y;
#pragma unroll
  for (int off = 32; off; off >>= 1) { s += __shfl_xor(s, off); q += __shfl_xor(q, off); }
  __shared__ float ssum[4], ssq[4];
  int wv = tid >> 6;
  if ((tid & 63) == 0) { ssum[wv] = s; ssq[wv] = q; }
  __syncthreads();
  s = ssum[0] + ssum[1] + ssum[2] + ssum[3];
  q = ssq[0] + ssq[1] + ssq[2] + ssq[3];
  float mu = s * (1.f / E_DIM);
  float var = q * (1.f / E_DIM) - mu * mu;
  float rs = rsqrtf(var + 1e-5f);
  int e = tid * 2;
  float2 o;
  o.x = (v.x - mu) * rs * w[e];
  o.y = (v.y - mu) * rs * w[e + 1];
  *(float2*)(out + (size_t)ridx * E_DIM + e) = o;
}

// ---------------- batched transpose f32 [L][K][N] -> bf16 [L][N][K] ----------------
__global__ __launch_bounds__(256) void transpose_bf16_all_kernel(
    const float* __restrict__ in0, u16* __restrict__ out0, int K, int N)
{
  __shared__ u16 T[64][72];
  int L = blockIdx.z;
  const float* in = in0 + (size_t)L * K * N;
  u16* out = out0 + (size_t)L * N * K;
  int k0 = blockIdx.x * 64, n0 = blockIdx.y * 64;
  int t = threadIdx.x;
  int kr = t >> 2, nseg = (t & 3) * 16;
  const float* src = in + (size_t)(k0 + kr) * N + n0 + nseg;
#pragma unroll
  for (int j = 0; j < 16; j++) T[kr][nseg + j] = f2bf(src[j]);
  __syncthreads();
  int nr = t >> 2, kseg = (t & 3) * 16;
  u32 u[8];
#pragma unroll
  for (int rr = 0; rr < 8; rr++) {
    u32 lo = T[kseg + 2 * rr][nr];
    u32 hi = T[kseg + 2 * rr + 1][nr];
    u[rr] = lo | (hi << 16);
  }
  u16* dst = out + (size_t)(n0 + nr) * K + k0 + kseg;
  uint4 w0 = {u[0], u[1], u[2], u[3]};
  uint4 w1 = {u[4], u[5], u[6], u[7]};
  *(uint4*)dst = w0;
  *(uint4*)(dst + 8) = w1;
}

// ---------------- bf16 MFMA GEMM 128x128; split C: C0 f32, C1 bf16 ----------------
__global__ __launch_bounds__(256) void gemm_bf16_split(
    const u16* __restrict__ A, const u16* __restrict__ Bt,
    float* __restrict__ C0, u16* __restrict__ C1,
    int M, int N, int K, int split_col, int ldc)
{
  __shared__ u16 As[128][40];
  __shared__ u16 Bs[128][40];
  const int tid = threadIdx.x;
  const int row0 = blockIdx.y * 128, col0 = blockIdx.x * 128;
  const int wave = tid >> 6, lane = tid & 63;
  const int wr = wave >> 1, wc = wave & 1;
  const int lm = lane & 15, lq = lane >> 4;
  const int sr = tid >> 1, sp = (tid & 1) * 16;
  f32x4 acc[4][4] = {};
  for (int k0 = 0; k0 < K; k0 += 32) {
    __syncthreads();
    const uint4* sa = (const uint4*)(A + (size_t)(row0 + sr) * K + k0 + sp);
    *(uint4*)&As[sr][sp] = sa[0];
    *(uint4*)&As[sr][sp + 8] = sa[1];
    const uint4* sb = (const uint4*)(Bt + (size_t)(col0 + sr) * K + k0 + sp);
    *(uint4*)&Bs[sr][sp] = sb[0];
    *(uint4*)&Bs[sr][sp + 8] = sb[1];
    __syncthreads();
    short8 af[4], bf[4];
#pragma unroll
    for (int i = 0; i < 4; i++) af[i] = *(const short8*)&As[wr * 64 + i * 16 + lm][lq * 8];
#pragma unroll
    for (int j = 0; j < 4; j++) bf[j] = *(const short8*)&Bs[wc * 64 + j * 16 + lm][lq * 8];
#pragma unroll
    for (int i = 0; i < 4; i++)
#pragma unroll
      for (int j = 0; j < 4; j++)
        acc[i][j] = __builtin_amdgcn_mfma_f32_16x16x32_bf16(af[i], bf[j], acc[i][j], 0, 0, 0);
  }
  const bool toC1 = (col0 >= split_col);
#pragma unroll
  for (int i = 0; i < 4; i++) {
#pragma unroll
    for (int j = 0; j < 4; j++) {
      int col = col0 - (toC1 ? split_col : 0) + wc * 64 + j * 16 + lm;
#pragma unroll
      for (int r = 0; r < 4; r++) {
        int row = row0 + wr * 64 + i * 16 + lq * 4 + r;
        if (toC1) C1[(size_t)row * ldc + col] = f2bf(acc[i][j][r]);
        else C0[(size_t)row * ldc + col] = acc[i][j][r];
      }
    }
  }
}

// ---------------- bf16 MFMA GEMM 64x64 (down-proj, +=) ----------------
__global__ __launch_bounds__(256) void gemm_bf16_64(
    const u16* __restrict__ A, const u16* __restrict__ Bt,
    float* __restrict__ C, int M, int N, int K, int ldc)
{
  __shared__ u16 As[64][40];
  __shared__ u16 Bs[64][40];
  const int tid = threadIdx.x;
  const int row0 = blockIdx.y * 64, col0 = blockIdx.x * 64;
  const int wave = tid >> 6, lane = tid & 63;
  const int wr = wave >> 1, wc = wave & 1;
  const int lm = lane & 15, lq = lane >> 4;
  const int sr = tid >> 2, sp = (tid & 3) * 8;
  f32x4 acc[2][2] = {};
  for (int k0 = 0; k0 < K; k0 += 32) {
    __syncthreads();
    *(uint4*)&As[sr][sp] = *(const uint4*)(A + (size_t)(row0 + sr) * K + k0 + sp);
    *(uint4*)&Bs[sr][sp] = *(const uint4*)(Bt + (size_t)(col0 + sr) * K + k0 + sp);
    __syncthreads();
    short8 af[2], bf[2];
#pragma unroll
    for (int i = 0; i < 2; i++) af[i] = *(const short8*)&As[wr * 32 + i * 16 + lm][lq * 8];
#pragma unroll
    for (int j = 0; j < 2; j++) bf[j] = *(const short8*)&Bs[wc * 32 + j * 16 + lm][lq * 8];
#pragma unroll
    for (int i = 0; i < 2; i++)
#pragma unroll
      for (int j = 0; j < 2; j++)
        acc[i][j] = __builtin_amdgcn_mfma_f32_16x16x32_bf16(af[i], bf[j], acc[i][j], 0, 0, 0);
  }
#pragma unroll
  for (int i = 0; i < 2; i++) {
#pragma unroll
    for (int j = 0; j < 2; j++) {
      int col = col0 + wc * 32 + j * 16 + lm;
#pragma unroll
      for (int r = 0; r < 4; r++) {
        int row = row0 + wr * 32 + i * 16 + lq * 4 + r;
        C[(size_t)row * ldc + col] += acc[i][j][r];
      }
    }
  }
}

// ---------------- fused conv+SiLU+qkv+gates (block = one row) ----------------
__global__ __launch_bounds__(256) void cqg_kernel(
    const float* __restrict__ xm,
    const float* __restrict__ cw, const float* __restrict__ cb,
    const float* __restrict__ qw, const float* __restrict__ kw, const float* __restrict__ vw,
    const float* __restrict__ igW, const float* __restrict__ igb,
    const float* __restrict__ fgW, const float* __restrict__ fgb,
    float* __restrict__ xc, u16* __restrict__ q, u16* __restrict__ k, u16* __restrict__ v,
    float* __restrict__ ig, float* __restrict__ fg)
{
  int row = blockIdx.x;           // b*S+s
  int b = row >> 10, s = row & (S_LEN - 1);
  int g = threadIdx.x;            // 0..255 (channel group of 4)
  int c0 = g * 4;
  const float* base = xm + (size_t)row * INNER_D + c0;

  // causal depthwise conv K=4 + bias + SiLU
  float4 acc = {0.f, 0.f, 0.f, 0.f};
  float4 xm4 = {0.f, 0.f, 0.f, 0.f};
#pragma unroll
  for (int kk = 0; kk < 4; kk++) {
    int ts = s - 3 + kk;
    float4 xv = {0.f, 0.f, 0.f, 0.f};
    if (ts >= 0) xv = *(const float4*)(base + (ptrdiff_t)(kk - 3) * INNER_D);
    if (kk == 3) xm4 = xv;
    acc.x += xv.x * cw[(c0 + 0) * 4 + kk];
    acc.y += xv.y * cw[(c0 + 1) * 4 + kk];
    acc.z += xv.z * cw[(c0 + 2) * 4 + kk];
    acc.w += xv.w * cw[(c0 + 3) * 4 + kk];
  }
  acc.x += cb[c0 + 0]; acc.y += cb[c0 + 1];
  acc.z += cb[c0 + 2]; acc.w += cb[c0 + 3];
  acc.x = acc.x / (1.f + __expf(-acc.x));
  acc.y = acc.y / (1.f + __expf(-acc.y));
  acc.z = acc.z / (1.f + __expf(-acc.z));
  acc.w = acc.w / (1.f + __expf(-acc.w));
  *(float4*)(xc + (size_t)row * INNER_D + c0) = acc;

  // headwise 4x4 projections
  const float* qg = qw + g * 16;
  const float* kg = kw + g * 16;
  const float* vg = vw + g * 16;
  float xcv[4] = {acc.x, acc.y, acc.z, acc.w};
  float xmv[4] = {xm4.x, xm4.y, xm4.z, xm4.w};
  ushort4 qs, ks, vs;
  u16* qp = (u16*)&qs; u16* kp = (u16*)&ks; u16* vp = (u16*)&vs;
  float qvr[4], kvr[4], vvr[4];
#pragma unroll
  for (int o = 0; o < 4; o++) {
    float aq = 0.f, ak = 0.f, av = 0.f;
#pragma unroll
    for (int d = 0; d < 4; d++) {
      aq += xcv[d] * qg[o * 4 + d];
      ak += xcv[d] * kg[o * 4 + d];
      av += xmv[d] * vg[o * 4 + d];
    }
    qp[o] = f2bf(aq); kp[o] = f2bf(ak); vp[o] = f2bf(av);
    qvr[o] = bf2f(qp[o]); kvr[o] = bf2f(kp[o]); vvr[o] = bf2f(vp[o]);
  }
  size_t off = (size_t)row * INNER_D + c0;
  *(ushort4*)(q + off) = qs;
  *(ushort4*)(k + off) = ks;
  *(ushort4*)(v + off) = vs;

  // gate GEMVs from register (rounded) values
  float ia[8] = {}, fa[8] = {};
#pragma unroll
  for (int part = 0; part < 3; part++) {
#pragma unroll
    for (int d = 0; d < 4; d++) {
      int j = part * 1024 + c0 + d;
      float xv = (part == 0) ? qvr[d] : (part == 1) ? kvr[d] : vvr[d];
      float4 wi0 = *(const float4*)(igW + (size_t)j * 8);
      float4 wi1 = *(const float4*)(igW + (size_t)j * 8 + 4);
      float4 wf0 = *(const float4*)(fgW + (size_t)j * 8);
      float4 wf1 = *(const float4*)(fgW + (size_t)j * 8 + 4);
      ia[0] += xv * wi0.x; ia[1] += xv * wi0.y; ia[2] += xv * wi0.z; ia[3] += xv * wi0.w;
      ia[4] += xv * wi1.x; ia[5] += xv * wi1.y; ia[6] += xv * wi1.z; ia[7] += xv * wi1.w;
      fa[0] += xv * wf0.x; fa[1] += xv * wf0.y; fa[2] += xv * wf0.z; fa[3] += xv * wf0.w;
      fa[4] += xv * wf1.x; fa[5] += xv * wf1.y; fa[6] += xv * wf1.z; fa[7] += xv * wf1.w;
    }
  }
#pragma unroll
  for (int offs = 32; offs; offs >>= 1) {
#pragma unroll
    for (int n = 0; n < 8; n++) {
      ia[n] += __shfl_xor(ia[n], offs);
      fa[n] += __shfl_xor(fa[n], offs);
    }
  }
  __shared__ float red[2][4][8];
  int wv = g >> 6;
  if ((g & 63) == 0) {
#pragma unroll
    for (int n = 0; n < 8; n++) { red[0][wv][n] = ia[n]; red[1][wv][n] = fa[n]; }
  }
  __syncthreads();
  if (g < 8) {
    float si = red[0][0][g] + red[0][1][g] + red[0][2][g] + red[0][3][g];
    float sf = red[1][0][g] + red[1][1][g] + red[1][2][g] + red[1][3][g];
    size_t o = ((size_t)(b * NHEAD + g) << 10) + s;
    ig[o] = si + igb[g];
    fg[o] = sf + fgb[g];
  }
}

// ---------------- per-(b,h) scans, shuffle-based ----------------
__global__ __launch_bounds__(1024) void scan_kernel(
    const float* __restrict__ ig, const float* __restrict__ fg,
    float* __restrict__ a, float* __restrict__ rm, float* __restrict__ enm)
{
  int bh = blockIdx.x;
  int t = threadIdx.x;
  int lane = t & 63, wv = t >> 6;
  __shared__ float sw[16];
  size_t o = ((size_t)bh << 10) + t;
  float f = fg[o];
  float lf = (f >= 0.f) ? -log1pf(__expf(-f)) : f - log1pf(__expf(f));
  float v = lf;
#pragma unroll
  for (int off = 1; off < 64; off <<= 1) {
    float u = __shfl_up(v, off);
    if (lane >= off) v += u;
  }
  if (lane == 63) sw[wv] = v;
  __syncthreads();
  float pre = 0.f;
  for (int w = 0; w < wv; w++) pre += sw[w];
  float cs = v + pre;
  float av = ig[o] - cs;
  a[o] = av;
  float m = av;
#pragma unroll
  for (int off = 1; off < 64; off <<= 1) {
    float u = __shfl_up(m, off);
    if (lane >= off) m = fmaxf(m, u);
  }
  __syncthreads();
  if (lane == 63) sw[wv] = m;
  __syncthreads();
  float pm = -3.4e38f;
  for (int w = 0; w < wv; w++) pm = fmaxf(pm, sw[w]);
  float rmx = fmaxf(m, pm);
  rm[o] = rmx;
  enm[o] = __expf(-(cs + rmx));
}

// ---------------- balanced split-K MFMA attention ----------------
__device__ __constant__ int c_qt[24] = {7,15,14,15, 6,13,14,12,13, 5,11,12,10,11, 4, 9,10, 8, 9, 3, 8, 2, 1, 0};
__device__ __constant__ int c_k0[24] = {0, 0, 7, 8, 0, 0, 0, 6, 7, 0, 0, 0, 5, 6, 0, 0, 0, 4, 5, 0, 0, 0, 0, 0};
__device__ __constant__ int c_k1[24] = {8, 8,15,16, 7, 7, 7,13,14, 6, 6, 6,11,12, 5, 5, 5, 9,10, 4, 4, 3, 2, 1};
__device__ __constant__ int c_md[24] = {0, 1, 2, 2, 0, 1, 1, 2, 2, 0, 1, 1, 2, 2, 0, 1, 1, 2, 2, 0, 1, 0, 0, 0};

__global__ __launch_bounds__(256) void attn_mfma_kernel(
    const u16* __restrict__ qhg, const u16* __restrict__ khg, const u16* __restrict__ vhg,
    const float* __restrict__ a_arr, const float* __restrict__ rm_arr, const float* __restrict__ enm_arr,
    const float* __restrict__ xc, const u16* __restrict__ zh,
    const float* __restrict__ skip, const float* __restrict__ onw,
    u16* __restrict__ hs, float* __restrict__ hpart, float* __restrict__ scpart)
{
  const int bh = blockIdx.x;
  const int job = blockIdx.y;
  const int qt = c_qt[job], k0t = c_k0[job], k1t = c_k1[job], mode = c_md[job];
  const int b = bh >> 3, h = bh & 7;
  const int s0 = qt * 64;
  const int tid = threadIdx.x;
  const int wave = tid >> 6, lane = tid & 63;
  const int lm = lane & 15, lq = lane >> 4;
  const size_t rowbase = (size_t)b * S_LEN;
  const int c0 = h * DHEAD;

  __shared__ u16 Ks[64 * 136];
  __shared__ u16 Vt[128 * 72];
  __shared__ u16 Ws[64 * 72];
  __shared__ float as_[64];

  short8 aq[4];
  {
    const u16* qp = qhg + (rowbase + s0 + wave * 16 + lm) * INNER_D + c0 + lq * 8;
#pragma unroll
    for (int kc = 0; kc < 4; kc++) {
      S8 tmp; tmp.q = *(const uint4*)(qp + kc * 32);
      aq[kc] = tmp.v;
    }
  }
  float rmv[4];
#pragma unroll
  for (int r = 0; r < 4; r++)
    rmv[r] = rm_arr[(size_t)bh * S_LEN + s0 + wave * 16 + lq * 4 + r];

  f32x4 accH[8] = {};
  float sc_acc[4] = {0.f, 0.f, 0.f, 0.f};
  const float scale = 0.08838834764831845f;  // 1/sqrt(128)

  for (int kt = k0t; kt < k1t; kt++) {
    const int t0 = kt * 64;
    __syncthreads();
#pragma unroll
    for (int rep = 0; rep < 4; rep++) {
      int idx = rep * 256 + tid;
      int r = idx >> 4, seg = (idx & 15) * 8;
      *(uint4*)&Ks[r * 136 + seg] =
          *(const uint4*)(khg + (rowbase + t0 + r) * INNER_D + c0 + seg);
    }
#pragma unroll
    for (int rep = 0; rep < 4; rep++) {
      int idx = rep * 256 + tid;
      int t = idx & 63, dgrp = idx >> 6;
      S8 vv;
      vv.q = *(const uint4*)(vhg + (rowbase + t0 + t) * INNER_D + c0 + dgrp * 8);
#pragma unroll
      for (int j = 0; j < 8; j++) Vt[(dgrp * 8 + j) * 72 + t] = vv.u[j];
    }
    if (tid < 64) as_[tid] = a_arr[(size_t)bh * S_LEN + t0 + tid];
    __syncthreads();

    f32x4 pacc[4] = {};
#pragma unroll
    for (int kc = 0; kc < 4; kc++) {
#pragma unroll
      for (int cb = 0; cb < 4; cb++) {
        short8 bk = *(const short8*)&Ks[(cb * 16 + lm) * 136 + kc * 32 + lq * 8];
        pacc[cb] = __builtin_amdgcn_mfma_f32_16x16x32_bf16(aq[kc], bk, pacc[cb], 0, 0, 0);
      }
    }

    float wpart[4] = {0.f, 0.f, 0.f, 0.f};
#pragma unroll
    for (int cb = 0; cb < 4; cb++) {
      int colg = t0 + cb * 16 + lm;
      float ea = as_[cb * 16 + lm];
#pragma unroll
      for (int r = 0; r < 4; r++) {
        int rowg = s0 + wave * 16 + lq * 4 + r;
        float wv = pacc[cb][r] * scale * __expf(ea - rmv[r]);
        if (colg > rowg) wv = 0.f;
        wpart[r] += wv;
        Ws[(wave * 16 + lq * 4 + r) * 72 + cb * 16 + lm] = f2bf(wv);
      }
    }
#pragma unroll
    for (int r = 0; r < 4; r++) {
      float sr = wpart[r];
      sr += __shfl_xor(sr, 1); sr += __shfl_xor(sr, 2);
      sr += __shfl_xor(sr, 4); sr += __shfl_xor(sr, 8);
      sc_acc[r] += sr;
    }

#pragma unroll
    for (int kc = 0; kc < 2; kc++) {
      short8 aw = *(const short8*)&Ws[(wave * 16 + lm) * 72 + kc * 32 + lq * 8];
#pragma unroll
      for (int nb = 0; nb < 8; nb++) {
        short8 bv = *(const short8*)&Vt[(nb * 16 + lm) * 72 + kc * 32 + lq * 8];
        accH[nb] = __builtin_amdgcn_mfma_f32_16x16x32_bf16(aw, bv, accH[nb], 0, 0, 0);
      }
    }
  }

  if (mode != 0) {
    int slot = mode - 1;
    int qr = qt - 8;
    float* Hp = hpart + (((size_t)slot * 16 + bh) * 8 + qr) * 8192;
    float* sp = scpart + ((slot * 16 + bh) * 8 + qr) * 64;
#pragma unroll
    for (int r = 0; r < 4; r++) {
      int row = wave * 16 + lq * 4 + r;
      if (lm == 0) sp[row] = sc_acc[r];
#pragma unroll
      for (int nb = 0; nb < 8; nb++)
        Hp[row * 128 + nb * 16 + lm] = accH[nb][r];
    }
    return;
  }

  float inv[4], muv[4], rsv[4];
#pragma unroll
  for (int r = 0; r < 4; r++) {
    int rowg = s0 + wave * 16 + lq * 4 + r;
    float nrm = fmaxf(fabsf(sc_acc[r]), enm_arr[(size_t)bh * S_LEN + rowg]);
    inv[r] = 1.f / (nrm + 1e-6f);
  }
#pragma unroll
  for (int r = 0; r < 4; r++) {
    float s = 0.f, qq = 0.f;
#pragma unroll
    for (int nb = 0; nb < 8; nb++) {
      float hv = accH[nb][r] * inv[r];
      accH[nb][r] = hv;
      s += hv; qq += hv * hv;
    }
    s += __shfl_xor(s, 1); s += __shfl_xor(s, 2); s += __shfl_xor(s, 4); s += __shfl_xor(s, 8);
    qq += __shfl_xor(qq, 1); qq += __shfl_xor(qq, 2); qq += __shfl_xor(qq, 4); qq += __shfl_xor(qq, 8);
    float mu = s * (1.f / DHEAD);
    float var = qq * (1.f / DHEAD) - mu * mu;
    muv[r] = mu;
    rsv[r] = rsqrtf(var + 1e-5f);
  }
  float ow[8], sk[8];
#pragma unroll
  for (int nb = 0; nb < 8; nb++) {
    ow[nb] = onw[c0 + nb * 16 + lm];
    sk[nb] = skip[c0 + nb * 16 + lm];
  }
#pragma unroll
  for (int r = 0; r < 4; r++) {
    int rowg = s0 + wave * 16 + lq * 4 + r;
    size_t base = (rowbase + rowg) * INNER_D + c0;
#pragma unroll
    for (int nb = 0; nb < 8; nb++) {
      int d = nb * 16 + lm;
      float xcv = xc[base + d];
      float zv = bf2f(zh[base + d]);
      float hn = (accH[nb][r] - muv[r]) * rsv[r] * ow[nb] + sk[nb] * xcv;
      float o = hn * (zv / (1.f + __expf(-zv)));
      hs[base + d] = f2bf(o);
    }
  }
}

// combine two partial slots for rows s >= 512; one wave per row.
__global__ __launch_bounds__(256) void attn_combine_kernel(
    const float* __restrict__ hpart, const float* __restrict__ scpart,
    const float* __restrict__ enm,
    const float* __restrict__ xc, const u16* __restrict__ zh,
    const float* __restrict__ skip, const float* __restrict__ onw,
    u16* __restrict__ hs)
{
  int wave = threadIdx.x >> 6, lane = threadIdx.x & 63;
  int gid = blockIdx.x * 4 + wave;
  int bh = gid >> 9;
  int rr = gid & 511;
  int qr = rr >> 6, row = rr & 63;
  int b = bh >> 3, hh = bh & 7;
  int s = (qr + 8) * 64 + row;
  size_t off = (((size_t)bh) * 8 + qr) * 8192 + row * 128 + lane * 2;
  float2 h0 = *(const float2*)(hpart + off);
  float2 h1 = *(const float2*)(hpart + 1048576 + off);
  int sidx = (bh * 8 + qr) * 64 + row;
  float sc = scpart[sidx] + scpart[8192 + sidx];
  float nrm = fmaxf(fabsf(sc), enm[(size_t)bh * S_LEN + s]);
  float inv = 1.f / (nrm + 1e-6f);
  float hx = (h0.x + h1.x) * inv, hy = (h0.y + h1.y) * inv;
  float sm = hx + hy, sq = hx * hx + hy * hy;
#pragma unroll
  for (int off2 = 32; off2; off2 >>= 1) { sm += __shfl_xor(sm, off2); sq += __shfl_xor(sq, off2); }
  float mu = sm * (1.f / DHEAD);
  float var = sq * (1.f / DHEAD) - mu * mu;
  float rs = rsqrtf(var + 1e-5f);
  int c0 = hh * DHEAD + lane * 2;
  size_t base = ((size_t)(b * S_LEN + s)) * INNER_D + c0;
  float2 xc2 = *(const float2*)(xc + base);
  ushort2 z2u = *(const ushort2*)(zh + base);
  float z2x = bf2f(z2u.x), z2y = bf2f(z2u.y);
  float skx = skip[c0], sky = skip[c0 + 1];
  float owx = onw[c0],  owy = onw[c0 + 1];
  ushort2 o;
  o.x = f2bf(((hx - mu) * rs * owx + skx * xc2.x) * (z2x / (1.f + __expf(-z2x))));
  o.y = f2bf(((hy - mu) * rs * owy + sky * xc2.y) * (z2y / (1.f + __expf(-z2y))));
  *(ushort2*)(hs + base) = o;
}

// ---------------- head ----------------
__global__ __launch_bounds__(64) void head_kernel(
    const float* __restrict__ ln96, const float* __restrict__ hW, const float* __restrict__ hb,
    float* __restrict__ out)
{
  int row = blockIdx.x;
  int n = threadIdx.x;
  if (n >= 21) return;
  float acc = hb[n];
  const float* xr = ln96 + (size_t)row * E_DIM;
  for (int kk = 0; kk < E_DIM; kk++) acc += xr[kk] * hW[kk * 21 + n];
  out[row * 21 + n] = acc;
}

extern "C" void kernel_launch(void* const* d_in, const int* in_sizes, int n_in,
                              void* d_out, int out_size, void* d_ws, size_t ws_size,
                              hipStream_t stream)
{
  const float* x_enc   = (const float*)d_in[0];
  const float* x_mark  = (const float*)d_in[1];
  const float* emb_W   = (const float*)d_in[4];
  const float* emb_b   = (const float*)d_in[5];
  const float* ln_w    = (const float*)d_in[6];
  const float* up_W    = (const float*)d_in[7];
  const float* conv_W  = (const float*)d_in[8];
  const float* conv_b  = (const float*)d_in[9];
  const float* q_W     = (const float*)d_in[10];
  const float* k_W     = (const float*)d_in[11];
  const float* v_W     = (const float*)d_in[12];
  const float* ig_W    = (const float*)d_in[13];
  const float* ig_b    = (const float*)d_in[14];
  const float* fg_W    = (const float*)d_in[15];
  const float* fg_b    = (const float*)d_in[16];
  const float* skip_w  = (const float*)d_in[17];
  const float* onorm_w = (const float*)d_in[18];
  const float* down_W  = (const float*)d_in[19];
  const float* post_ln = (const float*)d_in[20];
  const float* head_W  = (const float*)d_in[21];
  const float* head_b  = (const float*)d_in[22];

  float* p = (float*)d_ws;
  float* x    = p; p += 1048576;   // 2048*512 f32
  float* xm   = p; p += 2097152;   // 2048*1024 f32; reused as hsbh bf16 after cqg
  float* xc   = p; p += 2097152;
  float* igb_ = p; p += 16384;
  float* fgb_ = p; p += 16384;
  float* ab   = p; p += 16384;
  float* rmb  = p; p += 16384;
  float* enmb = p; p += 16384;
  float* ln96 = p; p += 98304;
  u16* qhb = (u16*)p; p += 1048576;  // 2048*1024 u16
  u16* khb = (u16*)p; p += 1048576;
  u16* vhb = (u16*)p; p += 1048576;
  u16* zh  = (u16*)p; p += 524288;   // 2048*1024 u16
  u16* xnh = (u16*)p; p += 524288;   // 2048*512 u16
  u16* upWtA = (u16*)p; p += 2097152; // 4 layers x 2048x512 u16 (8 MB)
  u16* dnWtA = (u16*)p; p += 1048576; // 4 layers x 512x1024 u16 (4 MB)
  float* hpart = p; p += 2097152;     // 2 x 16 x 8 x 64 x 128 f32
  float* scpart = p; p += 16384;
  u16* hsbh = (u16*)xm;
  // total ~14.8M floats = 59 MB

  embed_kernel<<<2048, 128, 0, stream>>>(x_enc, x_mark, emb_W, emb_b, x);
  transpose_bf16_all_kernel<<<dim3(8, 32, 4), 256, 0, stream>>>(up_W, upWtA, 512, 2048);
  transpose_bf16_all_kernel<<<dim3(16, 8, 4), 256, 0, stream>>>(down_W, dnWtA, 1024, 512);

  for (int L = 0; L < 4; L++) {
    ln_kernel<<<2048, 256, 0, stream>>>(x, ln_w + L * 512, xnh);
    gemm_bf16_split<<<dim3(16, 16), 256, 0, stream>>>(
        xnh, upWtA + (size_t)L * 1048576, xm, zh, 2048, 2048, 512, 1024, 1024);
    cqg_kernel<<<2048, 256, 0, stream>>>(
        xm, conv_W + L * 4096, conv_b + L * 1024,
        q_W + L * 4096, k_W + L * 4096, v_W + L * 4096,
        ig_W + L * 24576, ig_b + L * 8, fg_W + L * 24576, fg_b + L * 8,
        xc, qhb, khb, vhb, igb_, fgb_);
    scan_kernel<<<16, 1024, 0, stream>>>(igb_, fgb_, ab, rmb, enmb);
    attn_mfma_kernel<<<dim3(16, 24), 256, 0, stream>>>(
        qhb, khb, vhb, ab, rmb, enmb, xc, zh,
        skip_w + L * 1024, onorm_w + L * 1024, hsbh, hpart, scpart);
    attn_combine_kernel<<<2048, 256, 0, stream>>>(
        hpart, scpart, enmb, xc, zh, skip_w + L * 1024, onorm_w + L * 1024, hsbh);
    gemm_bf16_64<<<dim3(8, 32), 256, 0, stream>>>(
        hsbh, dnWtA + (size_t)L * 524288, x, 2048, 512, 1024, 512);
  }

  ln_final_kernel<<<192, 256, 0, stream>>>(x, post_ln, ln96);
  head_kernel<<<192, 64, 0, stream>>>(ln96, head_W, head_b, (float*)d_out);
}

// Round 13
// 638.111 us; speedup vs baseline: 1.2585x; 1.2585x over previous
//
#include <hip/hip_runtime.h>
#include <hip/hip_bf16.h>

#define S_LEN 1024
#define E_DIM 512
#define INNER_D 1024
#define NHEAD 8
#define DHEAD 128

typedef unsigned short u16;
typedef unsigned int u32;
typedef __attribute__((ext_vector_type(8))) short short8;
typedef __attribute__((ext_vector_type(4))) float f32x4;

union S8 { short8 v; u16 u[8]; uint4 q; };

__device__ __forceinline__ u16 f2bf(float f) {
  u32 u = __float_as_uint(f);
  u32 r = u + 0x7FFFu + ((u >> 16) & 1u);
  return (u16)(r >> 16);
}
__device__ __forceinline__ float bf2f(u16 u) { return __uint_as_float(((u32)u) << 16); }

// ---------------- embedding ----------------
__global__ __launch_bounds__(128) void embed_kernel(
    const float* __restrict__ xe, const float* __restrict__ xm,
    const float* __restrict__ W, const float* __restrict__ bias,
    float* __restrict__ x)
{
  int row = blockIdx.x;
  int tid = threadIdx.x;
  __shared__ float in_s[25];
  if (tid < 21) in_s[tid] = xe[row * 21 + tid];
  else if (tid < 25) in_s[tid] = xm[row * 4 + tid - 21];
  __syncthreads();
#pragma unroll
  for (int rep = 0; rep < 4; rep++) {
    int e = tid + rep * 128;
    float acc = bias[e];
#pragma unroll
    for (int i = 0; i < 25; i++) acc += in_s[i] * W[i * E_DIM + e];
    x[(size_t)row * E_DIM + e] = acc;
  }
}

// ---------------- layernorm -> bf16 ----------------
__global__ __launch_bounds__(256) void ln_kernel(
    const float* __restrict__ x, const float* __restrict__ w, u16* __restrict__ out)
{
  int row = blockIdx.x, tid = threadIdx.x;
  const float* xr = x + (size_t)row * E_DIM;
  float2 v = *(const float2*)(xr + tid * 2);
  float s = v.x + v.y, q = v.x * v.x + v.y * v.y;
#pragma unroll
  for (int off = 32; off; off >>= 1) { s += __shfl_xor(s, off); q += __shfl_xor(q, off); }
  __shared__ float ssum[4], ssq[4];
  int wv = tid >> 6;
  if ((tid & 63) == 0) { ssum[wv] = s; ssq[wv] = q; }
  __syncthreads();
  s = ssum[0] + ssum[1] + ssum[2] + ssum[3];
  q = ssq[0] + ssq[1] + ssq[2] + ssq[3];
  float mu = s * (1.f / E_DIM);
  float var = q * (1.f / E_DIM) - mu * mu;
  float rs = rsqrtf(var + 1e-5f);
  int e = tid * 2;
  ushort2 o;
  o.x = f2bf((v.x - mu) * rs * w[e]);
  o.y = f2bf((v.y - mu) * rs * w[e + 1]);
  *(ushort2*)(out + (size_t)row * E_DIM + e) = o;
}

__global__ __launch_bounds__(256) void ln_final_kernel(
    const float* __restrict__ x, const float* __restrict__ w, float* __restrict__ out)
{
  int ridx = blockIdx.x;
  int b = ridx / 96, r = ridx % 96;
  int row = b * S_LEN + (S_LEN - 96) + r;
  int tid = threadIdx.x;
  const float* xr = x + (size_t)row * E_DIM;
  float2 v = *(const float2*)(xr + tid * 2);
  float s = v.x + v.y, q = v.x * v.x + v.y * v.y;
#pragma unroll
  for (int off = 32; off; off >>= 1) { s += __shfl_xor(s, off); q += __shfl_xor(q, off); }
  __shared__ float ssum[4], ssq[4];
  int wv = tid >> 6;
  if ((tid & 63) == 0) { ssum[wv] = s; ssq[wv] = q; }
  __syncthreads();
  s = ssum[0] + ssum[1] + ssum[2] + ssum[3];
  q = ssq[0] + ssq[1] + ssq[2] + ssq[3];
  float mu = s * (1.f / E_DIM);
  float var = q * (1.f / E_DIM) - mu * mu;
  float rs = rsqrtf(var + 1e-5f);
  int e = tid * 2;
  float2 o;
  o.x = (v.x - mu) * rs * w[e];
  o.y = (v.y - mu) * rs * w[e + 1];
  *(float2*)(out + (size_t)ridx * E_DIM + e) = o;
}

// ---------------- batched transpose f32 [L][K][N] -> bf16 [L][N][K] ----------------
__global__ __launch_bounds__(256) void transpose_bf16_all_kernel(
    const float* __restrict__ in0, u16* __restrict__ out0, int K, int N)
{
  __shared__ u16 T[64][72];
  int L = blockIdx.z;
  const float* in = in0 + (size_t)L * K * N;
  u16* out = out0 + (size_t)L * N * K;
  int k0 = blockIdx.x * 64, n0 = blockIdx.y * 64;
  int t = threadIdx.x;
  int kr = t >> 2, nseg = (t & 3) * 16;
  const float* src = in + (size_t)(k0 + kr) * N + n0 + nseg;
#pragma unroll
  for (int j = 0; j < 16; j++) T[kr][nseg + j] = f2bf(src[j]);
  __syncthreads();
  int nr = t >> 2, kseg = (t & 3) * 16;
  u32 u[8];
#pragma unroll
  for (int rr = 0; rr < 8; rr++) {
    u32 lo = T[kseg + 2 * rr][nr];
    u32 hi = T[kseg + 2 * rr + 1][nr];
    u[rr] = lo | (hi << 16);
  }
  u16* dst = out + (size_t)(n0 + nr) * K + k0 + kseg;
  uint4 w0 = {u[0], u[1], u[2], u[3]};
  uint4 w1 = {u[4], u[5], u[6], u[7]};
  *(uint4*)dst = w0;
  *(uint4*)(dst + 8) = w1;
}

// ---------------- gates weight transpose: igW/fgW [L][3072][8] f32 -> hi/lo [L][16][3072] bf16 ----
__global__ __launch_bounds__(256) void gates_w_transpose_kernel(
    const float* __restrict__ igW, const float* __restrict__ fgW,
    u16* __restrict__ hi, u16* __restrict__ lo)
{
  int L = blockIdx.z;
  int n = blockIdx.y;                      // 0..15
  int k = blockIdx.x * 256 + threadIdx.x;  // 0..3071
  const float* W = ((n < 8) ? igW : fgW) + (size_t)L * 24576;
  float v = W[(size_t)k * 8 + (n & 7)];
  u16 h = f2bf(v);
  u16 l = f2bf(v - bf2f(h));
  size_t o = ((size_t)L * 16 + n) * 3072 + k;
  hi[o] = h;
  lo[o] = l;
}

// ---------------- bf16 MFMA GEMM 128x128; split C: C0 f32, C1 bf16 ----------------
__global__ __launch_bounds__(256) void gemm_bf16_split(
    const u16* __restrict__ A, const u16* __restrict__ Bt,
    float* __restrict__ C0, u16* __restrict__ C1,
    int M, int N, int K, int split_col, int ldc)
{
  __shared__ u16 As[128][40];
  __shared__ u16 Bs[128][40];
  const int tid = threadIdx.x;
  const int row0 = blockIdx.y * 128, col0 = blockIdx.x * 128;
  const int wave = tid >> 6, lane = tid & 63;
  const int wr = wave >> 1, wc = wave & 1;
  const int lm = lane & 15, lq = lane >> 4;
  const int sr = tid >> 1, sp = (tid & 1) * 16;
  f32x4 acc[4][4] = {};
  for (int k0 = 0; k0 < K; k0 += 32) {
    __syncthreads();
    const uint4* sa = (const uint4*)(A + (size_t)(row0 + sr) * K + k0 + sp);
    *(uint4*)&As[sr][sp] = sa[0];
    *(uint4*)&As[sr][sp + 8] = sa[1];
    const uint4* sb = (const uint4*)(Bt + (size_t)(col0 + sr) * K + k0 + sp);
    *(uint4*)&Bs[sr][sp] = sb[0];
    *(uint4*)&Bs[sr][sp + 8] = sb[1];
    __syncthreads();
    short8 af[4], bf[4];
#pragma unroll
    for (int i = 0; i < 4; i++) af[i] = *(const short8*)&As[wr * 64 + i * 16 + lm][lq * 8];
#pragma unroll
    for (int j = 0; j < 4; j++) bf[j] = *(const short8*)&Bs[wc * 64 + j * 16 + lm][lq * 8];
#pragma unroll
    for (int i = 0; i < 4; i++)
#pragma unroll
      for (int j = 0; j < 4; j++)
        acc[i][j] = __builtin_amdgcn_mfma_f32_16x16x32_bf16(af[i], bf[j], acc[i][j], 0, 0, 0);
  }
  const bool toC1 = (col0 >= split_col);
#pragma unroll
  for (int i = 0; i < 4; i++) {
#pragma unroll
    for (int j = 0; j < 4; j++) {
      int col = col0 - (toC1 ? split_col : 0) + wc * 64 + j * 16 + lm;
#pragma unroll
      for (int r = 0; r < 4; r++) {
        int row = row0 + wr * 64 + i * 16 + lq * 4 + r;
        if (toC1) C1[(size_t)row * ldc + col] = f2bf(acc[i][j][r]);
        else C0[(size_t)row * ldc + col] = acc[i][j][r];
      }
    }
  }
}

// ---------------- bf16 MFMA GEMM 64x64 (down-proj, +=) ----------------
__global__ __launch_bounds__(256) void gemm_bf16_64(
    const u16* __restrict__ A, const u16* __restrict__ Bt,
    float* __restrict__ C, int M, int N, int K, int ldc)
{
  __shared__ u16 As[64][40];
  __shared__ u16 Bs[64][40];
  const int tid = threadIdx.x;
  const int row0 = blockIdx.y * 64, col0 = blockIdx.x * 64;
  const int wave = tid >> 6, lane = tid & 63;
  const int wr = wave >> 1, wc = wave & 1;
  const int lm = lane & 15, lq = lane >> 4;
  const int sr = tid >> 2, sp = (tid & 3) * 8;
  f32x4 acc[2][2] = {};
  for (int k0 = 0; k0 < K; k0 += 32) {
    __syncthreads();
    *(uint4*)&As[sr][sp] = *(const uint4*)(A + (size_t)(row0 + sr) * K + k0 + sp);
    *(uint4*)&Bs[sr][sp] = *(const uint4*)(Bt + (size_t)(col0 + sr) * K + k0 + sp);
    __syncthreads();
    short8 af[2], bf[2];
#pragma unroll
    for (int i = 0; i < 2; i++) af[i] = *(const short8*)&As[wr * 32 + i * 16 + lm][lq * 8];
#pragma unroll
    for (int j = 0; j < 2; j++) bf[j] = *(const short8*)&Bs[wc * 32 + j * 16 + lm][lq * 8];
#pragma unroll
    for (int i = 0; i < 2; i++)
#pragma unroll
      for (int j = 0; j < 2; j++)
        acc[i][j] = __builtin_amdgcn_mfma_f32_16x16x32_bf16(af[i], bf[j], acc[i][j], 0, 0, 0);
  }
#pragma unroll
  for (int i = 0; i < 2; i++) {
#pragma unroll
    for (int j = 0; j < 2; j++) {
      int col = col0 + wc * 32 + j * 16 + lm;
#pragma unroll
      for (int r = 0; r < 4; r++) {
        int row = row0 + wr * 32 + i * 16 + lq * 4 + r;
        C[(size_t)row * ldc + col] += acc[i][j][r];
      }
    }
  }
}

// ---------------- causal depthwise conv (K=4) + bias + SiLU ----------------
__global__ __launch_bounds__(256) void conv_silu_kernel(
    const float* __restrict__ xm, const float* __restrict__ cw, const float* __restrict__ cb,
    float* __restrict__ xc)
{
  int idx = blockIdx.x * 256 + threadIdx.x;
  int g = idx & 255;
  int row = idx >> 8;
  int s = row & (S_LEN - 1);
  int c0 = g * 4;
  const float* base = xm + (size_t)row * INNER_D + c0;
  float4 acc = {0.f, 0.f, 0.f, 0.f};
#pragma unroll
  for (int kk = 0; kk < 4; kk++) {
    int ts = s - 3 + kk;
    if (ts >= 0) {
      float4 xv = *(const float4*)(base + (ptrdiff_t)(kk - 3) * INNER_D);
      acc.x += xv.x * cw[(c0 + 0) * 4 + kk];
      acc.y += xv.y * cw[(c0 + 1) * 4 + kk];
      acc.z += xv.z * cw[(c0 + 2) * 4 + kk];
      acc.w += xv.w * cw[(c0 + 3) * 4 + kk];
    }
  }
  acc.x += cb[c0 + 0]; acc.y += cb[c0 + 1];
  acc.z += cb[c0 + 2]; acc.w += cb[c0 + 3];
  acc.x = acc.x / (1.f + __expf(-acc.x));
  acc.y = acc.y / (1.f + __expf(-acc.y));
  acc.z = acc.z / (1.f + __expf(-acc.z));
  acc.w = acc.w / (1.f + __expf(-acc.w));
  *(float4*)(xc + (size_t)row * INNER_D + c0) = acc;
}

// ---------------- headwise 4x4 projections -> bf16 q,k,v ----------------
__global__ __launch_bounds__(256) void qkv_headwise_kernel(
    const float* __restrict__ xc, const float* __restrict__ xm,
    const float* __restrict__ qw, const float* __restrict__ kw, const float* __restrict__ vw,
    u16* __restrict__ q, u16* __restrict__ k, u16* __restrict__ v)
{
  int idx = blockIdx.x * 256 + threadIdx.x;
  int g = idx & 255;
  size_t row = idx >> 8;
  float4 xc4 = *(const float4*)(xc + row * INNER_D + g * 4);
  float4 xm4 = *(const float4*)(xm + row * INNER_D + g * 4);
  const float* qg = qw + g * 16;
  const float* kg = kw + g * 16;
  const float* vg = vw + g * 16;
  float xcv[4] = {xc4.x, xc4.y, xc4.z, xc4.w};
  float xmv[4] = {xm4.x, xm4.y, xm4.z, xm4.w};
  ushort4 qs, ks, vs;
  u16* qp = (u16*)&qs; u16* kp = (u16*)&ks; u16* vp = (u16*)&vs;
#pragma unroll
  for (int o = 0; o < 4; o++) {
    float aq = 0.f, ak = 0.f, av = 0.f;
#pragma unroll
    for (int d = 0; d < 4; d++) {
      aq += xcv[d] * qg[o * 4 + d];
      ak += xcv[d] * kg[o * 4 + d];
      av += xmv[d] * vg[o * 4 + d];
    }
    qp[o] = f2bf(aq); kp[o] = f2bf(ak); vp[o] = f2bf(av);
  }
  size_t off = row * INNER_D + g * 4;
  *(ushort4*)(q + off) = qs;
  *(ushort4*)(k + off) = ks;
  *(ushort4*)(v + off) = vs;
}

// ---------------- gates as skinny MFMA GEMM: C[2048,16] = qkv[2048,3072] @ W^T ----------------
// W pre-transposed hi/lo [16][3072] bf16 (hi+lo = fp32-exact). 128 blocks x 16 rows.
// Wave w covers k in [w*768,(w+1)*768); cross-wave reduce in LDS.
__global__ __launch_bounds__(256) void gates_mfma_kernel(
    const u16* __restrict__ q, const u16* __restrict__ k, const u16* __restrict__ v,
    const u16* __restrict__ whi, const u16* __restrict__ wlo,
    const float* __restrict__ igb, const float* __restrict__ fgb,
    float* __restrict__ ig, float* __restrict__ fg)
{
  const int blk = blockIdx.x;      // 0..127
  const int tid = threadIdx.x;
  const int wave = tid >> 6, lane = tid & 63;
  const int lm = lane & 15, lq = lane >> 4;
  const int grow = blk * 16 + lm;  // global row for A operand
  const u16* parts[3] = {q, k, v};
  f32x4 acc = {};
#pragma unroll 4
  for (int kc = 0; kc < 24; kc++) {
    int k0 = wave * 768 + kc * 32;
    int part = k0 >> 10;
    int idx = (k0 & 1023) + lq * 8;
    S8 a, bh_, bl_;
    a.q = *(const uint4*)(parts[part] + (size_t)grow * INNER_D + idx);
    bh_.q = *(const uint4*)(whi + (size_t)lm * 3072 + k0 + lq * 8);
    bl_.q = *(const uint4*)(wlo + (size_t)lm * 3072 + k0 + lq * 8);
    acc = __builtin_amdgcn_mfma_f32_16x16x32_bf16(a.v, bh_.v, acc, 0, 0, 0);
    acc = __builtin_amdgcn_mfma_f32_16x16x32_bf16(a.v, bl_.v, acc, 0, 0, 0);
  }
  __shared__ float red[4][16][17];
#pragma unroll
  for (int r = 0; r < 4; r++) red[wave][lq * 4 + r][lm] = acc[r];
  __syncthreads();
  if (wave == 0) {
#pragma unroll
    for (int r = 0; r < 4; r++) {
      int row = lq * 4 + r;  // 0..15
      float sum = red[0][row][lm] + red[1][row][lm] + red[2][row][lm] + red[3][row][lm];
      int growr = blk * 16 + row;
      int b = growr >> 10, s = growr & (S_LEN - 1);
      if (lm < 8) ig[((size_t)(b * NHEAD + lm) << 10) + s] = sum + igb[lm];
      else        fg[((size_t)(b * NHEAD + (lm - 8)) << 10) + s] = sum + fgb[lm - 8];
    }
  }
}

// ---------------- per-(b,h) scans, shuffle-based ----------------
__global__ __launch_bounds__(1024) void scan_kernel(
    const float* __restrict__ ig, const float* __restrict__ fg,
    float* __restrict__ a, float* __restrict__ rm, float* __restrict__ enm)
{
  int bh = blockIdx.x;
  int t = threadIdx.x;
  int lane = t & 63, wv = t >> 6;
  __shared__ float sw[16];
  size_t o = ((size_t)bh << 10) + t;
  float f = fg[o];
  float lf = (f >= 0.f) ? -log1pf(__expf(-f)) : f - log1pf(__expf(f));
  float v = lf;
#pragma unroll
  for (int off = 1; off < 64; off <<= 1) {
    float u = __shfl_up(v, off);
    if (lane >= off) v += u;
  }
  if (lane == 63) sw[wv] = v;
  __syncthreads();
  float pre = 0.f;
  for (int w = 0; w < wv; w++) pre += sw[w];
  float cs = v + pre;
  float av = ig[o] - cs;
  a[o] = av;
  float m = av;
#pragma unroll
  for (int off = 1; off < 64; off <<= 1) {
    float u = __shfl_up(m, off);
    if (lane >= off) m = fmaxf(m, u);
  }
  __syncthreads();
  if (lane == 63) sw[wv] = m;
  __syncthreads();
  float pm = -3.4e38f;
  for (int w = 0; w < wv; w++) pm = fmaxf(pm, sw[w]);
  float rmx = fmaxf(m, pm);
  rm[o] = rmx;
  enm[o] = __expf(-(cs + rmx));
}

// ---------------- balanced split-K MFMA attention ----------------
__device__ __constant__ int c_qt[24] = {7,15,14,15, 6,13,14,12,13, 5,11,12,10,11, 4, 9,10, 8, 9, 3, 8, 2, 1, 0};
__device__ __constant__ int c_k0[24] = {0, 0, 7, 8, 0, 0, 0, 6, 7, 0, 0, 0, 5, 6, 0, 0, 0, 4, 5, 0, 0, 0, 0, 0};
__device__ __constant__ int c_k1[24] = {8, 8,15,16, 7, 7, 7,13,14, 6, 6, 6,11,12, 5, 5, 5, 9,10, 4, 4, 3, 2, 1};
__device__ __constant__ int c_md[24] = {0, 1, 2, 2, 0, 1, 1, 2, 2, 0, 1, 1, 2, 2, 0, 1, 1, 2, 2, 0, 1, 0, 0, 0};

__global__ __launch_bounds__(256) void attn_mfma_kernel(
    const u16* __restrict__ qhg, const u16* __restrict__ khg, const u16* __restrict__ vhg,
    const float* __restrict__ a_arr, const float* __restrict__ rm_arr, const float* __restrict__ enm_arr,
    const float* __restrict__ xc, const u16* __restrict__ zh,
    const float* __restrict__ skip, const float* __restrict__ onw,
    u16* __restrict__ hs, float* __restrict__ hpart, float* __restrict__ scpart)
{
  const int bh = blockIdx.x;
  const int job = blockIdx.y;
  const int qt = c_qt[job], k0t = c_k0[job], k1t = c_k1[job], mode = c_md[job];
  const int b = bh >> 3, h = bh & 7;
  const int s0 = qt * 64;
  const int tid = threadIdx.x;
  const int wave = tid >> 6, lane = tid & 63;
  const int lm = lane & 15, lq = lane >> 4;
  const size_t rowbase = (size_t)b * S_LEN;
  const int c0 = h * DHEAD;

  __shared__ u16 Ks[64 * 136];
  __shared__ u16 Vt[128 * 72];
  __shared__ u16 Ws[64 * 72];
  __shared__ float as_[64];

  short8 aq[4];
  {
    const u16* qp = qhg + (rowbase + s0 + wave * 16 + lm) * INNER_D + c0 + lq * 8;
#pragma unroll
    for (int kc = 0; kc < 4; kc++) {
      S8 tmp; tmp.q = *(const uint4*)(qp + kc * 32);
      aq[kc] = tmp.v;
    }
  }
  float rmv[4];
#pragma unroll
  for (int r = 0; r < 4; r++)
    rmv[r] = rm_arr[(size_t)bh * S_LEN + s0 + wave * 16 + lq * 4 + r];

  f32x4 accH[8] = {};
  float sc_acc[4] = {0.f, 0.f, 0.f, 0.f};
  const float scale = 0.08838834764831845f;  // 1/sqrt(128)

  for (int kt = k0t; kt < k1t; kt++) {
    const int t0 = kt * 64;
    __syncthreads();
#pragma unroll
    for (int rep = 0; rep < 4; rep++) {
      int idx = rep * 256 + tid;
      int r = idx >> 4, seg = (idx & 15) * 8;
      *(uint4*)&Ks[r * 136 + seg] =
          *(const uint4*)(khg + (rowbase + t0 + r) * INNER_D + c0 + seg);
    }
#pragma unroll
    for (int rep = 0; rep < 4; rep++) {
      int idx = rep * 256 + tid;
      int t = idx & 63, dgrp = idx >> 6;
      S8 vv;
      vv.q = *(const uint4*)(vhg + (rowbase + t0 + t) * INNER_D + c0 + dgrp * 8);
#pragma unroll
      for (int j = 0; j < 8; j++) Vt[(dgrp * 8 + j) * 72 + t] = vv.u[j];
    }
    if (tid < 64) as_[tid] = a_arr[(size_t)bh * S_LEN + t0 + tid];
    __syncthreads();

    f32x4 pacc[4] = {};
#pragma unroll
    for (int kc = 0; kc < 4; kc++) {
#pragma unroll
      for (int cb = 0; cb < 4; cb++) {
        short8 bk = *(const short8*)&Ks[(cb * 16 + lm) * 136 + kc * 32 + lq * 8];
        pacc[cb] = __builtin_amdgcn_mfma_f32_16x16x32_bf16(aq[kc], bk, pacc[cb], 0, 0, 0);
      }
    }

    float wpart[4] = {0.f, 0.f, 0.f, 0.f};
#pragma unroll
    for (int cb = 0; cb < 4; cb++) {
      int colg = t0 + cb * 16 + lm;
      float ea = as_[cb * 16 + lm];
#pragma unroll
      for (int r = 0; r < 4; r++) {
        int rowg = s0 + wave * 16 + lq * 4 + r;
        float wv = pacc[cb][r] * scale * __expf(ea - rmv[r]);
        if (colg > rowg) wv = 0.f;
        wpart[r] += wv;
        Ws[(wave * 16 + lq * 4 + r) * 72 + cb * 16 + lm] = f2bf(wv);
      }
    }
#pragma unroll
    for (int r = 0; r < 4; r++) {
      float sr = wpart[r];
      sr += __shfl_xor(sr, 1); sr += __shfl_xor(sr, 2);
      sr += __shfl_xor(sr, 4); sr += __shfl_xor(sr, 8);
      sc_acc[r] += sr;
    }

#pragma unroll
    for (int kc = 0; kc < 2; kc++) {
      short8 aw = *(const short8*)&Ws[(wave * 16 + lm) * 72 + kc * 32 + lq * 8];
#pragma unroll
      for (int nb = 0; nb < 8; nb++) {
        short8 bv = *(const short8*)&Vt[(nb * 16 + lm) * 72 + kc * 32 + lq * 8];
        accH[nb] = __builtin_amdgcn_mfma_f32_16x16x32_bf16(aw, bv, accH[nb], 0, 0, 0);
      }
    }
  }

  if (mode != 0) {
    int slot = mode - 1;
    int qr = qt - 8;
    float* Hp = hpart + (((size_t)slot * 16 + bh) * 8 + qr) * 8192;
    float* sp = scpart + ((slot * 16 + bh) * 8 + qr) * 64;
#pragma unroll
    for (int r = 0; r < 4; r++) {
      int row = wave * 16 + lq * 4 + r;
      if (lm == 0) sp[row] = sc_acc[r];
#pragma unroll
      for (int nb = 0; nb < 8; nb++)
        Hp[row * 128 + nb * 16 + lm] = accH[nb][r];
    }
    return;
  }

  float inv[4], muv[4], rsv[4];
#pragma unroll
  for (int r = 0; r < 4; r++) {
    int rowg = s0 + wave * 16 + lq * 4 + r;
    float nrm = fmaxf(fabsf(sc_acc[r]), enm_arr[(size_t)bh * S_LEN + rowg]);
    inv[r] = 1.f / (nrm + 1e-6f);
  }
#pragma unroll
  for (int r = 0; r < 4; r++) {
    float s = 0.f, qq = 0.f;
#pragma unroll
    for (int nb = 0; nb < 8; nb++) {
      float hv = accH[nb][r] * inv[r];
      accH[nb][r] = hv;
      s += hv; qq += hv * hv;
    }
    s += __shfl_xor(s, 1); s += __shfl_xor(s, 2); s += __shfl_xor(s, 4); s += __shfl_xor(s, 8);
    qq += __shfl_xor(qq, 1); qq += __shfl_xor(qq, 2); qq += __shfl_xor(qq, 4); qq += __shfl_xor(qq, 8);
    float mu = s * (1.f / DHEAD);
    float var = qq * (1.f / DHEAD) - mu * mu;
    muv[r] = mu;
    rsv[r] = rsqrtf(var + 1e-5f);
  }
  float ow[8], sk[8];
#pragma unroll
  for (int nb = 0; nb < 8; nb++) {
    ow[nb] = onw[c0 + nb * 16 + lm];
    sk[nb] = skip[c0 + nb * 16 + lm];
  }
#pragma unroll
  for (int r = 0; r < 4; r++) {
    int rowg = s0 + wave * 16 + lq * 4 + r;
    size_t base = (rowbase + rowg) * INNER_D + c0;
#pragma unroll
    for (int nb = 0; nb < 8; nb++) {
      int d = nb * 16 + lm;
      float xcv = xc[base + d];
      float zv = bf2f(zh[base + d]);
      float hn = (accH[nb][r] - muv[r]) * rsv[r] * ow[nb] + sk[nb] * xcv;
      float o = hn * (zv / (1.f + __expf(-zv)));
      hs[base + d] = f2bf(o);
    }
  }
}

// combine two partial slots for rows s >= 512; one wave per row.
__global__ __launch_bounds__(256) void attn_combine_kernel(
    const float* __restrict__ hpart, const float* __restrict__ scpart,
    const float* __restrict__ enm,
    const float* __restrict__ xc, const u16* __restrict__ zh,
    const float* __restrict__ skip, const float* __restrict__ onw,
    u16* __restrict__ hs)
{
  int wave = threadIdx.x >> 6, lane = threadIdx.x & 63;
  int gid = blockIdx.x * 4 + wave;
  int bh = gid >> 9;
  int rr = gid & 511;
  int qr = rr >> 6, row = rr & 63;
  int b = bh >> 3, hh = bh & 7;
  int s = (qr + 8) * 64 + row;
  size_t off = (((size_t)bh) * 8 + qr) * 8192 + row * 128 + lane * 2;
  float2 h0 = *(const float2*)(hpart + off);
  float2 h1 = *(const float2*)(hpart + 1048576 + off);
  int sidx = (bh * 8 + qr) * 64 + row;
  float sc = scpart[sidx] + scpart[8192 + sidx];
  float nrm = fmaxf(fabsf(sc), enm[(size_t)bh * S_LEN + s]);
  float inv = 1.f / (nrm + 1e-6f);
  float hx = (h0.x + h1.x) * inv, hy = (h0.y + h1.y) * inv;
  float sm = hx + hy, sq = hx * hx + hy * hy;
#pragma unroll
  for (int off2 = 32; off2; off2 >>= 1) { sm += __shfl_xor(sm, off2); sq += __shfl_xor(sq, off2); }
  float mu = sm * (1.f / DHEAD);
  float var = sq * (1.f / DHEAD) - mu * mu;
  float rs = rsqrtf(var + 1e-5f);
  int c0 = hh * DHEAD + lane * 2;
  size_t base = ((size_t)(b * S_LEN + s)) * INNER_D + c0;
  float2 xc2 = *(const float2*)(xc + base);
  ushort2 z2u = *(const ushort2*)(zh + base);
  float z2x = bf2f(z2u.x), z2y = bf2f(z2u.y);
  float skx = skip[c0], sky = skip[c0 + 1];
  float owx = onw[c0],  owy = onw[c0 + 1];
  ushort2 o;
  o.x = f2bf(((hx - mu) * rs * owx + skx * xc2.x) * (z2x / (1.f + __expf(-z2x))));
  o.y = f2bf(((hy - mu) * rs * owy + sky * xc2.y) * (z2y / (1.f + __expf(-z2y))));
  *(ushort2*)(hs + base) = o;
}

// ---------------- head ----------------
__global__ __launch_bounds__(64) void head_kernel(
    const float* __restrict__ ln96, const float* __restrict__ hW, const float* __restrict__ hb,
    float* __restrict__ out)
{
  int row = blockIdx.x;
  int n = threadIdx.x;
  if (n >= 21) return;
  float acc = hb[n];
  const float* xr = ln96 + (size_t)row * E_DIM;
  for (int kk = 0; kk < E_DIM; kk++) acc += xr[kk] * hW[kk * 21 + n];
  out[row * 21 + n] = acc;
}

extern "C" void kernel_launch(void* const* d_in, const int* in_sizes, int n_in,
                              void* d_out, int out_size, void* d_ws, size_t ws_size,
                              hipStream_t stream)
{
  const float* x_enc   = (const float*)d_in[0];
  const float* x_mark  = (const float*)d_in[1];
  const float* emb_W   = (const float*)d_in[4];
  const float* emb_b   = (const float*)d_in[5];
  const float* ln_w    = (const float*)d_in[6];
  const float* up_W    = (const float*)d_in[7];
  const float* conv_W  = (const float*)d_in[8];
  const float* conv_b  = (const float*)d_in[9];
  const float* q_W     = (const float*)d_in[10];
  const float* k_W     = (const float*)d_in[11];
  const float* v_W     = (const float*)d_in[12];
  const float* ig_W    = (const float*)d_in[13];
  const float* ig_b    = (const float*)d_in[14];
  const float* fg_W    = (const float*)d_in[15];
  const float* fg_b    = (const float*)d_in[16];
  const float* skip_w  = (const float*)d_in[17];
  const float* onorm_w = (const float*)d_in[18];
  const float* down_W  = (const float*)d_in[19];
  const float* post_ln = (const float*)d_in[20];
  const float* head_W  = (const float*)d_in[21];
  const float* head_b  = (const float*)d_in[22];

  float* p = (float*)d_ws;
  float* x    = p; p += 1048576;   // 2048*512 f32
  float* xm   = p; p += 2097152;   // 2048*1024 f32; reused as hsbh bf16 after qkv
  float* xc   = p; p += 2097152;
  float* igb_ = p; p += 16384;
  float* fgb_ = p; p += 16384;
  float* ab   = p; p += 16384;
  float* rmb  = p; p += 16384;
  float* enmb = p; p += 16384;
  float* ln96 = p; p += 98304;
  u16* qhb = (u16*)p; p += 1048576;  // 2048*1024 u16
  u16* khb = (u16*)p; p += 1048576;
  u16* vhb = (u16*)p; p += 1048576;
  u16* zh  = (u16*)p; p += 524288;   // 2048*1024 u16
  u16* xnh = (u16*)p; p += 524288;   // 2048*512 u16
  u16* upWtA = (u16*)p; p += 2097152; // 4 x 2048x512 u16
  u16* dnWtA = (u16*)p; p += 1048576; // 4 x 512x1024 u16
  u16* gtwH = (u16*)p; p += 98304;    // 4 x 16 x 3072 u16
  u16* gtwL = (u16*)p; p += 98304;
  float* hpart = p; p += 2097152;     // 2 x 16 x 8 x 64 x 128 f32
  float* scpart = p; p += 16384;
  u16* hsbh = (u16*)xm;
  // total ~15.3M floats = 61 MB

  embed_kernel<<<2048, 128, 0, stream>>>(x_enc, x_mark, emb_W, emb_b, x);
  transpose_bf16_all_kernel<<<dim3(8, 32, 4), 256, 0, stream>>>(up_W, upWtA, 512, 2048);
  transpose_bf16_all_kernel<<<dim3(16, 8, 4), 256, 0, stream>>>(down_W, dnWtA, 1024, 512);
  gates_w_transpose_kernel<<<dim3(12, 16, 4), 256, 0, stream>>>(ig_W, fg_W, gtwH, gtwL);

  for (int L = 0; L < 4; L++) {
    ln_kernel<<<2048, 256, 0, stream>>>(x, ln_w + L * 512, xnh);
    gemm_bf16_split<<<dim3(16, 16), 256, 0, stream>>>(
        xnh, upWtA + (size_t)L * 1048576, xm, zh, 2048, 2048, 512, 1024, 1024);
    conv_silu_kernel<<<2048, 256, 0, stream>>>(xm, conv_W + L * 4096, conv_b + L * 1024, xc);
    qkv_headwise_kernel<<<2048, 256, 0, stream>>>(
        xc, xm, q_W + L * 4096, k_W + L * 4096, v_W + L * 4096, qhb, khb, vhb);
    gates_mfma_kernel<<<128, 256, 0, stream>>>(
        qhb, khb, vhb, gtwH + (size_t)L * 49152, gtwL + (size_t)L * 49152,
        ig_b + L * 8, fg_b + L * 8, igb_, fgb_);
    scan_kernel<<<16, 1024, 0, stream>>>(igb_, fgb_, ab, rmb, enmb);
    attn_mfma_kernel<<<dim3(16, 24), 256, 0, stream>>>(
        qhb, khb, vhb, ab, rmb, enmb, xc, zh,
        skip_w + L * 1024, onorm_w + L * 1024, hsbh, hpart, scpart);
    attn_combine_kernel<<<2048, 256, 0, stream>>>(
        hpart, scpart, enmb, xc, zh, skip_w + L * 1024, onorm_w + L * 1024, hsbh);
    gemm_bf16_64<<<dim3(8, 32), 256, 0, stream>>>(
        hsbh, dnWtA + (size_t)L * 524288, x, 2048, 512, 1024, 512);
  }

  ln_final_kernel<<<192, 256, 0, stream>>>(x, post_ln, ln96);
  head_kernel<<<192, 64, 0, stream>>>(ln96, head_W, head_b, (float*)d_out);
}

// Round 14
// 608.716 us; speedup vs baseline: 1.3193x; 1.0483x over previous
//
#include <hip/hip_runtime.h>
#include <hip/hip_bf16.h>

#define S_LEN 1024
#define E_DIM 512
#define INNER_D 1024
#define NHEAD 8
#define DHEAD 128

typedef unsigned short u16;
typedef unsigned int u32;
typedef __attribute__((ext_vector_type(8))) short short8;
typedef __attribute__((ext_vector_type(4))) float f32x4;

union S8 { short8 v; u16 u[8]; uint4 q; };

__device__ __forceinline__ u16 f2bf(float f) {
  u32 u = __float_as_uint(f);
  u32 r = u + 0x7FFFu + ((u >> 16) & 1u);
  return (u16)(r >> 16);
}
__device__ __forceinline__ float bf2f(u16 u) { return __uint_as_float(((u32)u) << 16); }

// ---------------- embedding ----------------
__global__ __launch_bounds__(128) void embed_kernel(
    const float* __restrict__ xe, const float* __restrict__ xm,
    const float* __restrict__ W, const float* __restrict__ bias,
    float* __restrict__ x)
{
  int row = blockIdx.x;
  int tid = threadIdx.x;
  __shared__ float in_s[25];
  if (tid < 21) in_s[tid] = xe[row * 21 + tid];
  else if (tid < 25) in_s[tid] = xm[row * 4 + tid - 21];
  __syncthreads();
#pragma unroll
  for (int rep = 0; rep < 4; rep++) {
    int e = tid + rep * 128;
    float acc = bias[e];
#pragma unroll
    for (int i = 0; i < 25; i++) acc += in_s[i] * W[i * E_DIM + e];
    x[(size_t)row * E_DIM + e] = acc;
  }
}

// ---------------- layernorm -> bf16 ----------------
__global__ __launch_bounds__(256) void ln_kernel(
    const float* __restrict__ x, const float* __restrict__ w, u16* __restrict__ out)
{
  int row = blockIdx.x, tid = threadIdx.x;
  const float* xr = x + (size_t)row * E_DIM;
  float2 v = *(const float2*)(xr + tid * 2);
  float s = v.x + v.y, q = v.x * v.x + v.y * v.y;
#pragma unroll
  for (int off = 32; off; off >>= 1) { s += __shfl_xor(s, off); q += __shfl_xor(q, off); }
  __shared__ float ssum[4], ssq[4];
  int wv = tid >> 6;
  if ((tid & 63) == 0) { ssum[wv] = s; ssq[wv] = q; }
  __syncthreads();
  s = ssum[0] + ssum[1] + ssum[2] + ssum[3];
  q = ssq[0] + ssq[1] + ssq[2] + ssq[3];
  float mu = s * (1.f / E_DIM);
  float var = q * (1.f / E_DIM) - mu * mu;
  float rs = rsqrtf(var + 1e-5f);
  int e = tid * 2;
  ushort2 o;
  o.x = f2bf((v.x - mu) * rs * w[e]);
  o.y = f2bf((v.y - mu) * rs * w[e + 1]);
  *(ushort2*)(out + (size_t)row * E_DIM + e) = o;
}

__global__ __launch_bounds__(256) void ln_final_kernel(
    const float* __restrict__ x, const float* __restrict__ w, float* __restrict__ out)
{
  int ridx = blockIdx.x;
  int b = ridx / 96, r = ridx % 96;
  int row = b * S_LEN + (S_LEN - 96) + r;
  int tid = threadIdx.x;
  const float* xr = x + (size_t)row * E_DIM;
  float2 v = *(const float2*)(xr + tid * 2);
  float s = v.x + v.y, q = v.x * v.x + v.y * v.y;
#pragma unroll
  for (int off = 32; off; off >>= 1) { s += __shfl_xor(s, off); q += __shfl_xor(q, off); }
  __shared__ float ssum[4], ssq[4];
  int wv = tid >> 6;
  if ((tid & 63) == 0) { ssum[wv] = s; ssq[wv] = q; }
  __syncthreads();
  s = ssum[0] + ssum[1] + ssum[2] + ssum[3];
  q = ssq[0] + ssq[1] + ssq[2] + ssq[3];
  float mu = s * (1.f / E_DIM);
  float var = q * (1.f / E_DIM) - mu * mu;
  float rs = rsqrtf(var + 1e-5f);
  int e = tid * 2;
  float2 o;
  o.x = (v.x - mu) * rs * w[e];
  o.y = (v.y - mu) * rs * w[e + 1];
  *(float2*)(out + (size_t)ridx * E_DIM + e) = o;
}

// ---------------- batched transpose f32 [L][K][N] -> bf16 [L][N][K] ----------------
__global__ __launch_bounds__(256) void transpose_bf16_all_kernel(
    const float* __restrict__ in0, u16* __restrict__ out0, int K, int N)
{
  __shared__ u16 T[64][72];
  int L = blockIdx.z;
  const float* in = in0 + (size_t)L * K * N;
  u16* out = out0 + (size_t)L * N * K;
  int k0 = blockIdx.x * 64, n0 = blockIdx.y * 64;
  int t = threadIdx.x;
  int kr = t >> 2, nseg = (t & 3) * 16;
  const float* src = in + (size_t)(k0 + kr) * N + n0 + nseg;
#pragma unroll
  for (int j = 0; j < 16; j++) T[kr][nseg + j] = f2bf(src[j]);
  __syncthreads();
  int nr = t >> 2, kseg = (t & 3) * 16;
  u32 u[8];
#pragma unroll
  for (int rr = 0; rr < 8; rr++) {
    u32 lo = T[kseg + 2 * rr][nr];
    u32 hi = T[kseg + 2 * rr + 1][nr];
    u[rr] = lo | (hi << 16);
  }
  u16* dst = out + (size_t)(n0 + nr) * K + k0 + kseg;
  uint4 w0 = {u[0], u[1], u[2], u[3]};
  uint4 w1 = {u[4], u[5], u[6], u[7]};
  *(uint4*)dst = w0;
  *(uint4*)(dst + 8) = w1;
}

// ---------------- gates weight transpose: igW/fgW [L][3072][8] f32 -> hi/lo [L][16][3072] bf16 ----
__global__ __launch_bounds__(256) void gates_w_transpose_kernel(
    const float* __restrict__ igW, const float* __restrict__ fgW,
    u16* __restrict__ hi, u16* __restrict__ lo)
{
  int L = blockIdx.z;
  int n = blockIdx.y;                      // 0..15
  int k = blockIdx.x * 256 + threadIdx.x;  // 0..3071
  const float* W = ((n < 8) ? igW : fgW) + (size_t)L * 24576;
  float v = W[(size_t)k * 8 + (n & 7)];
  u16 h = f2bf(v);
  u16 l = f2bf(v - bf2f(h));
  size_t o = ((size_t)L * 16 + n) * 3072 + k;
  hi[o] = h;
  lo[o] = l;
}

// ---------------- bf16 MFMA GEMM 128x128; split C: C0 f32, C1 bf16 ----------------
__global__ __launch_bounds__(256) void gemm_bf16_split(
    const u16* __restrict__ A, const u16* __restrict__ Bt,
    float* __restrict__ C0, u16* __restrict__ C1,
    int M, int N, int K, int split_col, int ldc)
{
  __shared__ u16 As[128][40];
  __shared__ u16 Bs[128][40];
  const int tid = threadIdx.x;
  const int row0 = blockIdx.y * 128, col0 = blockIdx.x * 128;
  const int wave = tid >> 6, lane = tid & 63;
  const int wr = wave >> 1, wc = wave & 1;
  const int lm = lane & 15, lq = lane >> 4;
  const int sr = tid >> 1, sp = (tid & 1) * 16;
  f32x4 acc[4][4] = {};
  for (int k0 = 0; k0 < K; k0 += 32) {
    __syncthreads();
    const uint4* sa = (const uint4*)(A + (size_t)(row0 + sr) * K + k0 + sp);
    *(uint4*)&As[sr][sp] = sa[0];
    *(uint4*)&As[sr][sp + 8] = sa[1];
    const uint4* sb = (const uint4*)(Bt + (size_t)(col0 + sr) * K + k0 + sp);
    *(uint4*)&Bs[sr][sp] = sb[0];
    *(uint4*)&Bs[sr][sp + 8] = sb[1];
    __syncthreads();
    short8 af[4], bf[4];
#pragma unroll
    for (int i = 0; i < 4; i++) af[i] = *(const short8*)&As[wr * 64 + i * 16 + lm][lq * 8];
#pragma unroll
    for (int j = 0; j < 4; j++) bf[j] = *(const short8*)&Bs[wc * 64 + j * 16 + lm][lq * 8];
#pragma unroll
    for (int i = 0; i < 4; i++)
#pragma unroll
      for (int j = 0; j < 4; j++)
        acc[i][j] = __builtin_amdgcn_mfma_f32_16x16x32_bf16(af[i], bf[j], acc[i][j], 0, 0, 0);
  }
  const bool toC1 = (col0 >= split_col);
#pragma unroll
  for (int i = 0; i < 4; i++) {
#pragma unroll
    for (int j = 0; j < 4; j++) {
      int col = col0 - (toC1 ? split_col : 0) + wc * 64 + j * 16 + lm;
#pragma unroll
      for (int r = 0; r < 4; r++) {
        int row = row0 + wr * 64 + i * 16 + lq * 4 + r;
        if (toC1) C1[(size_t)row * ldc + col] = f2bf(acc[i][j][r]);
        else C0[(size_t)row * ldc + col] = acc[i][j][r];
      }
    }
  }
}

// ---------------- bf16 MFMA GEMM 64x64 (down-proj, +=) ----------------
__global__ __launch_bounds__(256) void gemm_bf16_64(
    const u16* __restrict__ A, const u16* __restrict__ Bt,
    float* __restrict__ C, int M, int N, int K, int ldc)
{
  __shared__ u16 As[64][40];
  __shared__ u16 Bs[64][40];
  const int tid = threadIdx.x;
  const int row0 = blockIdx.y * 64, col0 = blockIdx.x * 64;
  const int wave = tid >> 6, lane = tid & 63;
  const int wr = wave >> 1, wc = wave & 1;
  const int lm = lane & 15, lq = lane >> 4;
  const int sr = tid >> 2, sp = (tid & 3) * 8;
  f32x4 acc[2][2] = {};
  for (int k0 = 0; k0 < K; k0 += 32) {
    __syncthreads();
    *(uint4*)&As[sr][sp] = *(const uint4*)(A + (size_t)(row0 + sr) * K + k0 + sp);
    *(uint4*)&Bs[sr][sp] = *(const uint4*)(Bt + (size_t)(col0 + sr) * K + k0 + sp);
    __syncthreads();
    short8 af[2], bf[2];
#pragma unroll
    for (int i = 0; i < 2; i++) af[i] = *(const short8*)&As[wr * 32 + i * 16 + lm][lq * 8];
#pragma unroll
    for (int j = 0; j < 2; j++) bf[j] = *(const short8*)&Bs[wc * 32 + j * 16 + lm][lq * 8];
#pragma unroll
    for (int i = 0; i < 2; i++)
#pragma unroll
      for (int j = 0; j < 2; j++)
        acc[i][j] = __builtin_amdgcn_mfma_f32_16x16x32_bf16(af[i], bf[j], acc[i][j], 0, 0, 0);
  }
#pragma unroll
  for (int i = 0; i < 2; i++) {
#pragma unroll
    for (int j = 0; j < 2; j++) {
      int col = col0 + wc * 32 + j * 16 + lm;
#pragma unroll
      for (int r = 0; r < 4; r++) {
        int row = row0 + wr * 32 + i * 16 + lq * 4 + r;
        C[(size_t)row * ldc + col] += acc[i][j][r];
      }
    }
  }
}

// ---------------- fused causal conv+SiLU+headwise qkv (block = one row) ----------------
__global__ __launch_bounds__(256) void convqkv_kernel(
    const float* __restrict__ xm,
    const float* __restrict__ cw, const float* __restrict__ cb,
    const float* __restrict__ qw, const float* __restrict__ kw, const float* __restrict__ vw,
    float* __restrict__ xc, u16* __restrict__ q, u16* __restrict__ k, u16* __restrict__ v)
{
  int row = blockIdx.x;            // b*S+s
  int s = row & (S_LEN - 1);
  int g = threadIdx.x;             // channel group of 4
  int c0 = g * 4;
  const float* base = xm + (size_t)row * INNER_D + c0;

  float4 acc = {0.f, 0.f, 0.f, 0.f};
  float4 xm4 = {0.f, 0.f, 0.f, 0.f};
#pragma unroll
  for (int kk = 0; kk < 4; kk++) {
    int ts = s - 3 + kk;
    float4 xv = {0.f, 0.f, 0.f, 0.f};
    if (ts >= 0) xv = *(const float4*)(base + (ptrdiff_t)(kk - 3) * INNER_D);
    if (kk == 3) xm4 = xv;
    acc.x += xv.x * cw[(c0 + 0) * 4 + kk];
    acc.y += xv.y * cw[(c0 + 1) * 4 + kk];
    acc.z += xv.z * cw[(c0 + 2) * 4 + kk];
    acc.w += xv.w * cw[(c0 + 3) * 4 + kk];
  }
  acc.x += cb[c0 + 0]; acc.y += cb[c0 + 1];
  acc.z += cb[c0 + 2]; acc.w += cb[c0 + 3];
  acc.x = acc.x / (1.f + __expf(-acc.x));
  acc.y = acc.y / (1.f + __expf(-acc.y));
  acc.z = acc.z / (1.f + __expf(-acc.z));
  acc.w = acc.w / (1.f + __expf(-acc.w));
  *(float4*)(xc + (size_t)row * INNER_D + c0) = acc;

  const float* qg = qw + g * 16;
  const float* kg = kw + g * 16;
  const float* vg = vw + g * 16;
  float xcv[4] = {acc.x, acc.y, acc.z, acc.w};
  float xmv[4] = {xm4.x, xm4.y, xm4.z, xm4.w};
  ushort4 qs, ks, vs;
  u16* qp = (u16*)&qs; u16* kp = (u16*)&ks; u16* vp = (u16*)&vs;
#pragma unroll
  for (int o = 0; o < 4; o++) {
    float aq = 0.f, ak = 0.f, av = 0.f;
#pragma unroll
    for (int d = 0; d < 4; d++) {
      aq += xcv[d] * qg[o * 4 + d];
      ak += xcv[d] * kg[o * 4 + d];
      av += xmv[d] * vg[o * 4 + d];
    }
    qp[o] = f2bf(aq); kp[o] = f2bf(ak); vp[o] = f2bf(av);
  }
  size_t off = (size_t)row * INNER_D + c0;
  *(ushort4*)(q + off) = qs;
  *(ushort4*)(k + off) = ks;
  *(ushort4*)(v + off) = vs;
}

// ---------------- gates as skinny MFMA GEMM: C[2048,16] = qkv[2048,3072] @ W^T ----------------
__global__ __launch_bounds__(256) void gates_mfma_kernel(
    const u16* __restrict__ q, const u16* __restrict__ k, const u16* __restrict__ v,
    const u16* __restrict__ whi, const u16* __restrict__ wlo,
    const float* __restrict__ igb, const float* __restrict__ fgb,
    float* __restrict__ ig, float* __restrict__ fg)
{
  const int blk = blockIdx.x;      // 0..127
  const int tid = threadIdx.x;
  const int wave = tid >> 6, lane = tid & 63;
  const int lm = lane & 15, lq = lane >> 4;
  const int grow = blk * 16 + lm;
  const u16* parts[3] = {q, k, v};
  f32x4 acc = {};
#pragma unroll 4
  for (int kc = 0; kc < 24; kc++) {
    int k0 = wave * 768 + kc * 32;
    int part = k0 >> 10;
    int idx = (k0 & 1023) + lq * 8;
    S8 a, bh_, bl_;
    a.q = *(const uint4*)(parts[part] + (size_t)grow * INNER_D + idx);
    bh_.q = *(const uint4*)(whi + (size_t)lm * 3072 + k0 + lq * 8);
    bl_.q = *(const uint4*)(wlo + (size_t)lm * 3072 + k0 + lq * 8);
    acc = __builtin_amdgcn_mfma_f32_16x16x32_bf16(a.v, bh_.v, acc, 0, 0, 0);
    acc = __builtin_amdgcn_mfma_f32_16x16x32_bf16(a.v, bl_.v, acc, 0, 0, 0);
  }
  __shared__ float red[4][16][17];
#pragma unroll
  for (int r = 0; r < 4; r++) red[wave][lq * 4 + r][lm] = acc[r];
  __syncthreads();
  if (wave == 0) {
#pragma unroll
    for (int r = 0; r < 4; r++) {
      int row = lq * 4 + r;
      float sum = red[0][row][lm] + red[1][row][lm] + red[2][row][lm] + red[3][row][lm];
      int growr = blk * 16 + row;
      int b = growr >> 10, s = growr & (S_LEN - 1);
      if (lm < 8) ig[((size_t)(b * NHEAD + lm) << 10) + s] = sum + igb[lm];
      else        fg[((size_t)(b * NHEAD + (lm - 8)) << 10) + s] = sum + fgb[lm - 8];
    }
  }
}

// ---------------- per-(b,h) scans, shuffle-based ----------------
__global__ __launch_bounds__(1024) void scan_kernel(
    const float* __restrict__ ig, const float* __restrict__ fg,
    float* __restrict__ a, float* __restrict__ rm, float* __restrict__ enm)
{
  int bh = blockIdx.x;
  int t = threadIdx.x;
  int lane = t & 63, wv = t >> 6;
  __shared__ float sw[16];
  size_t o = ((size_t)bh << 10) + t;
  float f = fg[o];
  float lf = (f >= 0.f) ? -log1pf(__expf(-f)) : f - log1pf(__expf(f));
  float v = lf;
#pragma unroll
  for (int off = 1; off < 64; off <<= 1) {
    float u = __shfl_up(v, off);
    if (lane >= off) v += u;
  }
  if (lane == 63) sw[wv] = v;
  __syncthreads();
  float pre = 0.f;
  for (int w = 0; w < wv; w++) pre += sw[w];
  float cs = v + pre;
  float av = ig[o] - cs;
  a[o] = av;
  float m = av;
#pragma unroll
  for (int off = 1; off < 64; off <<= 1) {
    float u = __shfl_up(m, off);
    if (lane >= off) m = fmaxf(m, u);
  }
  __syncthreads();
  if (lane == 63) sw[wv] = m;
  __syncthreads();
  float pm = -3.4e38f;
  for (int w = 0; w < wv; w++) pm = fmaxf(pm, sw[w]);
  float rmx = fmaxf(m, pm);
  rm[o] = rmx;
  enm[o] = __expf(-(cs + rmx));
}

// ---------------- balanced split-K MFMA attention ----------------
__device__ __constant__ int c_qt[24] = {7,15,14,15, 6,13,14,12,13, 5,11,12,10,11, 4, 9,10, 8, 9, 3, 8, 2, 1, 0};
__device__ __constant__ int c_k0[24] = {0, 0, 7, 8, 0, 0, 0, 6, 7, 0, 0, 0, 5, 6, 0, 0, 0, 4, 5, 0, 0, 0, 0, 0};
__device__ __constant__ int c_k1[24] = {8, 8,15,16, 7, 7, 7,13,14, 6, 6, 6,11,12, 5, 5, 5, 9,10, 4, 4, 3, 2, 1};
__device__ __constant__ int c_md[24] = {0, 1, 2, 2, 0, 1, 1, 2, 2, 0, 1, 1, 2, 2, 0, 1, 1, 2, 2, 0, 1, 0, 0, 0};

__global__ __launch_bounds__(256) void attn_mfma_kernel(
    const u16* __restrict__ qhg, const u16* __restrict__ khg, const u16* __restrict__ vhg,
    const float* __restrict__ a_arr, const float* __restrict__ rm_arr, const float* __restrict__ enm_arr,
    const float* __restrict__ xc, const u16* __restrict__ zh,
    const float* __restrict__ skip, const float* __restrict__ onw,
    u16* __restrict__ hs, float* __restrict__ hpart, float* __restrict__ scpart)
{
  const int bh = blockIdx.x;
  const int job = blockIdx.y;
  const int qt = c_qt[job], k0t = c_k0[job], k1t = c_k1[job], mode = c_md[job];
  const int b = bh >> 3, h = bh & 7;
  const int s0 = qt * 64;
  const int tid = threadIdx.x;
  const int wave = tid >> 6, lane = tid & 63;
  const int lm = lane & 15, lq = lane >> 4;
  const size_t rowbase = (size_t)b * S_LEN;
  const int c0 = h * DHEAD;

  __shared__ u16 Ks[64 * 136];
  __shared__ u16 Vt[128 * 72];
  __shared__ u16 Ws[64 * 72];
  __shared__ float as_[64];

  short8 aq[4];
  {
    const u16* qp = qhg + (rowbase + s0 + wave * 16 + lm) * INNER_D + c0 + lq * 8;
#pragma unroll
    for (int kc = 0; kc < 4; kc++) {
      S8 tmp; tmp.q = *(const uint4*)(qp + kc * 32);
      aq[kc] = tmp.v;
    }
  }
  float rmv[4];
#pragma unroll
  for (int r = 0; r < 4; r++)
    rmv[r] = rm_arr[(size_t)bh * S_LEN + s0 + wave * 16 + lq * 4 + r];

  f32x4 accH[8] = {};
  float sc_acc[4] = {0.f, 0.f, 0.f, 0.f};
  const float scale = 0.08838834764831845f;  // 1/sqrt(128)

  for (int kt = k0t; kt < k1t; kt++) {
    const int t0 = kt * 64;
    __syncthreads();
#pragma unroll
    for (int rep = 0; rep < 4; rep++) {
      int idx = rep * 256 + tid;
      int r = idx >> 4, seg = (idx & 15) * 8;
      *(uint4*)&Ks[r * 136 + seg] =
          *(const uint4*)(khg + (rowbase + t0 + r) * INNER_D + c0 + seg);
    }
#pragma unroll
    for (int rep = 0; rep < 4; rep++) {
      int idx = rep * 256 + tid;
      int t = idx & 63, dgrp = idx >> 6;
      S8 vv;
      vv.q = *(const uint4*)(vhg + (rowbase + t0 + t) * INNER_D + c0 + dgrp * 8);
#pragma unroll
      for (int j = 0; j < 8; j++) Vt[(dgrp * 8 + j) * 72 + t] = vv.u[j];
    }
    if (tid < 64) as_[tid] = a_arr[(size_t)bh * S_LEN + t0 + tid];
    __syncthreads();

    f32x4 pacc[4] = {};
#pragma unroll
    for (int kc = 0; kc < 4; kc++) {
#pragma unroll
      for (int cb = 0; cb < 4; cb++) {
        short8 bk = *(const short8*)&Ks[(cb * 16 + lm) * 136 + kc * 32 + lq * 8];
        pacc[cb] = __builtin_amdgcn_mfma_f32_16x16x32_bf16(aq[kc], bk, pacc[cb], 0, 0, 0);
      }
    }

    float wpart[4] = {0.f, 0.f, 0.f, 0.f};
#pragma unroll
    for (int cb = 0; cb < 4; cb++) {
      int colg = t0 + cb * 16 + lm;
      float ea = as_[cb * 16 + lm];
#pragma unroll
      for (int r = 0; r < 4; r++) {
        int rowg = s0 + wave * 16 + lq * 4 + r;
        float wv = pacc[cb][r] * scale * __expf(ea - rmv[r]);
        if (colg > rowg) wv = 0.f;
        wpart[r] += wv;
        Ws[(wave * 16 + lq * 4 + r) * 72 + cb * 16 + lm] = f2bf(wv);
      }
    }
#pragma unroll
    for (int r = 0; r < 4; r++) {
      float sr = wpart[r];
      sr += __shfl_xor(sr, 1); sr += __shfl_xor(sr, 2);
      sr += __shfl_xor(sr, 4); sr += __shfl_xor(sr, 8);
      sc_acc[r] += sr;
    }

#pragma unroll
    for (int kc = 0; kc < 2; kc++) {
      short8 aw = *(const short8*)&Ws[(wave * 16 + lm) * 72 + kc * 32 + lq * 8];
#pragma unroll
      for (int nb = 0; nb < 8; nb++) {
        short8 bv = *(const short8*)&Vt[(nb * 16 + lm) * 72 + kc * 32 + lq * 8];
        accH[nb] = __builtin_amdgcn_mfma_f32_16x16x32_bf16(aw, bv, accH[nb], 0, 0, 0);
      }
    }
  }

  if (mode != 0) {
    int slot = mode - 1;
    int qr = qt - 8;
    float* Hp = hpart + (((size_t)slot * 16 + bh) * 8 + qr) * 8192;
    float* sp = scpart + ((slot * 16 + bh) * 8 + qr) * 64;
#pragma unroll
    for (int r = 0; r < 4; r++) {
      int row = wave * 16 + lq * 4 + r;
      if (lm == 0) sp[row] = sc_acc[r];
#pragma unroll
      for (int nb = 0; nb < 8; nb++)
        Hp[row * 128 + nb * 16 + lm] = accH[nb][r];
    }
    return;
  }

  float inv[4], muv[4], rsv[4];
#pragma unroll
  for (int r = 0; r < 4; r++) {
    int rowg = s0 + wave * 16 + lq * 4 + r;
    float nrm = fmaxf(fabsf(sc_acc[r]), enm_arr[(size_t)bh * S_LEN + rowg]);
    inv[r] = 1.f / (nrm + 1e-6f);
  }
#pragma unroll
  for (int r = 0; r < 4; r++) {
    float s = 0.f, qq = 0.f;
#pragma unroll
    for (int nb = 0; nb < 8; nb++) {
      float hv = accH[nb][r] * inv[r];
      accH[nb][r] = hv;
      s += hv; qq += hv * hv;
    }
    s += __shfl_xor(s, 1); s += __shfl_xor(s, 2); s += __shfl_xor(s, 4); s += __shfl_xor(s, 8);
    qq += __shfl_xor(qq, 1); qq += __shfl_xor(qq, 2); qq += __shfl_xor(qq, 4); qq += __shfl_xor(qq, 8);
    float mu = s * (1.f / DHEAD);
    float var = qq * (1.f / DHEAD) - mu * mu;
    muv[r] = mu;
    rsv[r] = rsqrtf(var + 1e-5f);
  }
  float ow[8], sk[8];
#pragma unroll
  for (int nb = 0; nb < 8; nb++) {
    ow[nb] = onw[c0 + nb * 16 + lm];
    sk[nb] = skip[c0 + nb * 16 + lm];
  }
#pragma unroll
  for (int r = 0; r < 4; r++) {
    int rowg = s0 + wave * 16 + lq * 4 + r;
    size_t base = (rowbase + rowg) * INNER_D + c0;
#pragma unroll
    for (int nb = 0; nb < 8; nb++) {
      int d = nb * 16 + lm;
      float xcv = xc[base + d];
      float zv = bf2f(zh[base + d]);
      float hn = (accH[nb][r] - muv[r]) * rsv[r] * ow[nb] + sk[nb] * xcv;
      float o = hn * (zv / (1.f + __expf(-zv)));
      hs[base + d] = f2bf(o);
    }
  }
}

// combine two partial slots for rows s >= 512; one wave per row.
__global__ __launch_bounds__(256) void attn_combine_kernel(
    const float* __restrict__ hpart, const float* __restrict__ scpart,
    const float* __restrict__ enm,
    const float* __restrict__ xc, const u16* __restrict__ zh,
    const float* __restrict__ skip, const float* __restrict__ onw,
    u16* __restrict__ hs)
{
  int wave = threadIdx.x >> 6, lane = threadIdx.x & 63;
  int gid = blockIdx.x * 4 + wave;
  int bh = gid >> 9;
  int rr = gid & 511;
  int qr = rr >> 6, row = rr & 63;
  int b = bh >> 3, hh = bh & 7;
  int s = (qr + 8) * 64 + row;
  size_t off = (((size_t)bh) * 8 + qr) * 8192 + row * 128 + lane * 2;
  float2 h0 = *(const float2*)(hpart + off);
  float2 h1 = *(const float2*)(hpart + 1048576 + off);
  int sidx = (bh * 8 + qr) * 64 + row;
  float sc = scpart[sidx] + scpart[8192 + sidx];
  float nrm = fmaxf(fabsf(sc), enm[(size_t)bh * S_LEN + s]);
  float inv = 1.f / (nrm + 1e-6f);
  float hx = (h0.x + h1.x) * inv, hy = (h0.y + h1.y) * inv;
  float sm = hx + hy, sq = hx * hx + hy * hy;
#pragma unroll
  for (int off2 = 32; off2; off2 >>= 1) { sm += __shfl_xor(sm, off2); sq += __shfl_xor(sq, off2); }
  float mu = sm * (1.f / DHEAD);
  float var = sq * (1.f / DHEAD) - mu * mu;
  float rs = rsqrtf(var + 1e-5f);
  int c0 = hh * DHEAD + lane * 2;
  size_t base = ((size_t)(b * S_LEN + s)) * INNER_D + c0;
  float2 xc2 = *(const float2*)(xc + base);
  ushort2 z2u = *(const ushort2*)(zh + base);
  float z2x = bf2f(z2u.x), z2y = bf2f(z2u.y);
  float skx = skip[c0], sky = skip[c0 + 1];
  float owx = onw[c0],  owy = onw[c0 + 1];
  ushort2 o;
  o.x = f2bf(((hx - mu) * rs * owx + skx * xc2.x) * (z2x / (1.f + __expf(-z2x))));
  o.y = f2bf(((hy - mu) * rs * owy + sky * xc2.y) * (z2y / (1.f + __expf(-z2y))));
  *(ushort2*)(hs + base) = o;
}

// ---------------- head ----------------
__global__ __launch_bounds__(64) void head_kernel(
    const float* __restrict__ ln96, const float* __restrict__ hW, const float* __restrict__ hb,
    float* __restrict__ out)
{
  int row = blockIdx.x;
  int n = threadIdx.x;
  if (n >= 21) return;
  float acc = hb[n];
  const float* xr = ln96 + (size_t)row * E_DIM;
  for (int kk = 0; kk < E_DIM; kk++) acc += xr[kk] * hW[kk * 21 + n];
  out[row * 21 + n] = acc;
}

extern "C" void kernel_launch(void* const* d_in, const int* in_sizes, int n_in,
                              void* d_out, int out_size, void* d_ws, size_t ws_size,
                              hipStream_t stream)
{
  const float* x_enc   = (const float*)d_in[0];
  const float* x_mark  = (const float*)d_in[1];
  const float* emb_W   = (const float*)d_in[4];
  const float* emb_b   = (const float*)d_in[5];
  const float* ln_w    = (const float*)d_in[6];
  const float* up_W    = (const float*)d_in[7];
  const float* conv_W  = (const float*)d_in[8];
  const float* conv_b  = (const float*)d_in[9];
  const float* q_W     = (const float*)d_in[10];
  const float* k_W     = (const float*)d_in[11];
  const float* v_W     = (const float*)d_in[12];
  const float* ig_W    = (const float*)d_in[13];
  const float* ig_b    = (const float*)d_in[14];
  const float* fg_W    = (const float*)d_in[15];
  const float* fg_b    = (const float*)d_in[16];
  const float* skip_w  = (const float*)d_in[17];
  const float* onorm_w = (const float*)d_in[18];
  const float* down_W  = (const float*)d_in[19];
  const float* post_ln = (const float*)d_in[20];
  const float* head_W  = (const float*)d_in[21];
  const float* head_b  = (const float*)d_in[22];

  float* p = (float*)d_ws;
  float* x    = p; p += 1048576;   // 2048*512 f32
  float* xm   = p; p += 2097152;   // 2048*1024 f32; reused as hsbh bf16 after convqkv
  float* xc   = p; p += 2097152;
  float* igb_ = p; p += 16384;
  float* fgb_ = p; p += 16384;
  float* ab   = p; p += 16384;
  float* rmb  = p; p += 16384;
  float* enmb = p; p += 16384;
  float* ln96 = p; p += 98304;
  u16* qhb = (u16*)p; p += 1048576;  // 2048*1024 u16
  u16* khb = (u16*)p; p += 1048576;
  u16* vhb = (u16*)p; p += 1048576;
  u16* zh  = (u16*)p; p += 524288;   // 2048*1024 u16
  u16* xnh = (u16*)p; p += 524288;   // 2048*512 u16
  u16* upWtA = (u16*)p; p += 2097152; // 4 x 2048x512 u16
  u16* dnWtA = (u16*)p; p += 1048576; // 4 x 512x1024 u16
  u16* gtwH = (u16*)p; p += 98304;    // 4 x 16 x 3072 u16
  u16* gtwL = (u16*)p; p += 98304;
  float* hpart = p; p += 2097152;     // 2 x 16 x 8 x 64 x 128 f32
  float* scpart = p; p += 16384;
  u16* hsbh = (u16*)xm;
  // total ~15.3M floats = 61 MB

  embed_kernel<<<2048, 128, 0, stream>>>(x_enc, x_mark, emb_W, emb_b, x);
  transpose_bf16_all_kernel<<<dim3(8, 32, 4), 256, 0, stream>>>(up_W, upWtA, 512, 2048);
  transpose_bf16_all_kernel<<<dim3(16, 8, 4), 256, 0, stream>>>(down_W, dnWtA, 1024, 512);
  gates_w_transpose_kernel<<<dim3(12, 16, 4), 256, 0, stream>>>(ig_W, fg_W, gtwH, gtwL);

  for (int L = 0; L < 4; L++) {
    ln_kernel<<<2048, 256, 0, stream>>>(x, ln_w + L * 512, xnh);
    gemm_bf16_split<<<dim3(16, 16), 256, 0, stream>>>(
        xnh, upWtA + (size_t)L * 1048576, xm, zh, 2048, 2048, 512, 1024, 1024);
    convqkv_kernel<<<2048, 256, 0, stream>>>(
        xm, conv_W + L * 4096, conv_b + L * 1024,
        q_W + L * 4096, k_W + L * 4096, v_W + L * 4096,
        xc, qhb, khb, vhb);
    gates_mfma_kernel<<<128, 256, 0, stream>>>(
        qhb, khb, vhb, gtwH + (size_t)L * 49152, gtwL + (size_t)L * 49152,
        ig_b + L * 8, fg_b + L * 8, igb_, fgb_);
    scan_kernel<<<16, 1024, 0, stream>>>(igb_, fgb_, ab, rmb, enmb);
    attn_mfma_kernel<<<dim3(16, 24), 256, 0, stream>>>(
        qhb, khb, vhb, ab, rmb, enmb, xc, zh,
        skip_w + L * 1024, onorm_w + L * 1024, hsbh, hpart, scpart);
    attn_combine_kernel<<<2048, 256, 0, stream>>>(
        hpart, scpart, enmb, xc, zh, skip_w + L * 1024, onorm_w + L * 1024, hsbh);
    gemm_bf16_64<<<dim3(8, 32), 256, 0, stream>>>(
        hsbh, dnWtA + (size_t)L * 524288, x, 2048, 512, 1024, 512);
  }

  ln_final_kernel<<<192, 256, 0, stream>>>(x, post_ln, ln96);
  head_kernel<<<192, 64, 0, stream>>>(ln96, head_W, head_b, (float*)d_out);
}

// Round 15
// 607.107 us; speedup vs baseline: 1.3228x; 1.0027x over previous
//
#include <hip/hip_runtime.h>
#include <hip/hip_bf16.h>

#define S_LEN 1024
#define E_DIM 512
#define INNER_D 1024
#define NHEAD 8
#define DHEAD 128

typedef unsigned short u16;
typedef unsigned int u32;
typedef __attribute__((ext_vector_type(8))) short short8;
typedef __attribute__((ext_vector_type(4))) float f32x4;

union S8 { short8 v; u16 u[8]; uint4 q; };

__device__ __forceinline__ u16 f2bf(float f) {
  u32 u = __float_as_uint(f);
  u32 r = u + 0x7FFFu + ((u >> 16) & 1u);
  return (u16)(r >> 16);
}
__device__ __forceinline__ float bf2f(u16 u) { return __uint_as_float(((u32)u) << 16); }

// ---------------- embedding ----------------
__global__ __launch_bounds__(128) void embed_kernel(
    const float* __restrict__ xe, const float* __restrict__ xm,
    const float* __restrict__ W, const float* __restrict__ bias,
    float* __restrict__ x)
{
  int row = blockIdx.x;
  int tid = threadIdx.x;
  __shared__ float in_s[25];
  if (tid < 21) in_s[tid] = xe[row * 21 + tid];
  else if (tid < 25) in_s[tid] = xm[row * 4 + tid - 21];
  __syncthreads();
#pragma unroll
  for (int rep = 0; rep < 4; rep++) {
    int e = tid + rep * 128;
    float acc = bias[e];
#pragma unroll
    for (int i = 0; i < 25; i++) acc += in_s[i] * W[i * E_DIM + e];
    x[(size_t)row * E_DIM + e] = acc;
  }
}

// ---------------- layernorm -> bf16 ----------------
__global__ __launch_bounds__(256) void ln_kernel(
    const float* __restrict__ x, const float* __restrict__ w, u16* __restrict__ out)
{
  int row = blockIdx.x, tid = threadIdx.x;
  const float* xr = x + (size_t)row * E_DIM;
  float2 v = *(const float2*)(xr + tid * 2);
  float s = v.x + v.y, q = v.x * v.x + v.y * v.y;
#pragma unroll
  for (int off = 32; off; off >>= 1) { s += __shfl_xor(s, off); q += __shfl_xor(q, off); }
  __shared__ float ssum[4], ssq[4];
  int wv = tid >> 6;
  if ((tid & 63) == 0) { ssum[wv] = s; ssq[wv] = q; }
  __syncthreads();
  s = ssum[0] + ssum[1] + ssum[2] + ssum[3];
  q = ssq[0] + ssq[1] + ssq[2] + ssq[3];
  float mu = s * (1.f / E_DIM);
  float var = q * (1.f / E_DIM) - mu * mu;
  float rs = rsqrtf(var + 1e-5f);
  int e = tid * 2;
  ushort2 o;
  o.x = f2bf((v.x - mu) * rs * w[e]);
  o.y = f2bf((v.y - mu) * rs * w[e + 1]);
  *(ushort2*)(out + (size_t)row * E_DIM + e) = o;
}

__global__ __launch_bounds__(256) void ln_final_kernel(
    const float* __restrict__ x, const float* __restrict__ w, float* __restrict__ out)
{
  int ridx = blockIdx.x;
  int b = ridx / 96, r = ridx % 96;
  int row = b * S_LEN + (S_LEN - 96) + r;
  int tid = threadIdx.x;
  const float* xr = x + (size_t)row * E_DIM;
  float2 v = *(const float2*)(xr + tid * 2);
  float s = v.x + v.y, q = v.x * v.x + v.y * v.y;
#pragma unroll
  for (int off = 32; off; off >>= 1) { s += __shfl_xor(s, off); q += __shfl_xor(q, off); }
  __shared__ float ssum[4], ssq[4];
  int wv = tid >> 6;
  if ((tid & 63) == 0) { ssum[wv] = s; ssq[wv] = q; }
  __syncthreads();
  s = ssum[0] + ssum[1] + ssum[2] + ssum[3];
  q = ssq[0] + ssq[1] + ssq[2] + ssq[3];
  float mu = s * (1.f / E_DIM);
  float var = q * (1.f / E_DIM) - mu * mu;
  float rs = rsqrtf(var + 1e-5f);
  int e = tid * 2;
  float2 o;
  o.x = (v.x - mu) * rs * w[e];
  o.y = (v.y - mu) * rs * w[e + 1];
  *(float2*)(out + (size_t)ridx * E_DIM + e) = o;
}

// ---------------- batched transpose f32 [L][K][N] -> bf16 [L][N][K] ----------------
__global__ __launch_bounds__(256) void transpose_bf16_all_kernel(
    const float* __restrict__ in0, u16* __restrict__ out0, int K, int N)
{
  __shared__ u16 T[64][72];
  int L = blockIdx.z;
  const float* in = in0 + (size_t)L * K * N;
  u16* out = out0 + (size_t)L * N * K;
  int k0 = blockIdx.x * 64, n0 = blockIdx.y * 64;
  int t = threadIdx.x;
  int kr = t >> 2, nseg = (t & 3) * 16;
  const float* src = in + (size_t)(k0 + kr) * N + n0 + nseg;
#pragma unroll
  for (int j = 0; j < 16; j++) T[kr][nseg + j] = f2bf(src[j]);
  __syncthreads();
  int nr = t >> 2, kseg = (t & 3) * 16;
  u32 u[8];
#pragma unroll
  for (int rr = 0; rr < 8; rr++) {
    u32 lo = T[kseg + 2 * rr][nr];
    u32 hi = T[kseg + 2 * rr + 1][nr];
    u[rr] = lo | (hi << 16);
  }
  u16* dst = out + (size_t)(n0 + nr) * K + k0 + kseg;
  uint4 w0 = {u[0], u[1], u[2], u[3]};
  uint4 w1 = {u[4], u[5], u[6], u[7]};
  *(uint4*)dst = w0;
  *(uint4*)(dst + 8) = w1;
}

// ---------------- gates weight transpose: igW/fgW [L][3072][8] f32 -> hi/lo [L][16][3072] bf16 ----
__global__ __launch_bounds__(256) void gates_w_transpose_kernel(
    const float* __restrict__ igW, const float* __restrict__ fgW,
    u16* __restrict__ hi, u16* __restrict__ lo)
{
  int L = blockIdx.z;
  int n = blockIdx.y;                      // 0..15
  int k = blockIdx.x * 256 + threadIdx.x;  // 0..3071
  const float* W = ((n < 8) ? igW : fgW) + (size_t)L * 24576;
  float v = W[(size_t)k * 8 + (n & 7)];
  u16 h = f2bf(v);
  u16 l = f2bf(v - bf2f(h));
  size_t o = ((size_t)L * 16 + n) * 3072 + k;
  hi[o] = h;
  lo[o] = l;
}

// ---------------- bf16 MFMA GEMM 64x128 (up-proj); split C: C0 f32, C1 bf16; 512 blocks ----------------
__global__ __launch_bounds__(256) void gemm_bf16_split64(
    const u16* __restrict__ A, const u16* __restrict__ Bt,
    float* __restrict__ C0, u16* __restrict__ C1,
    int M, int N, int K, int split_col, int ldc)
{
  __shared__ u16 As[64][40];
  __shared__ u16 Bs[128][40];
  const int tid = threadIdx.x;
  const int row0 = blockIdx.y * 64, col0 = blockIdx.x * 128;
  const int wave = tid >> 6, lane = tid & 63;
  const int wr = wave >> 1, wc = wave & 1;   // wave tile: 32 rows x 64 cols
  const int lm = lane & 15, lq = lane >> 4;
  const int srA = tid >> 2, spA = (tid & 3) * 8;    // 64 rows x 32 u16, 1 uint4/thread
  const int srB = tid >> 1, spB = (tid & 1) * 16;   // 128 rows x 32 u16, 2 uint4/thread
  f32x4 acc[2][4] = {};
  for (int k0 = 0; k0 < K; k0 += 32) {
    __syncthreads();
    *(uint4*)&As[srA][spA] = *(const uint4*)(A + (size_t)(row0 + srA) * K + k0 + spA);
    const uint4* sb = (const uint4*)(Bt + (size_t)(col0 + srB) * K + k0 + spB);
    *(uint4*)&Bs[srB][spB] = sb[0];
    *(uint4*)&Bs[srB][spB + 8] = sb[1];
    __syncthreads();
    short8 af[2], bf[4];
#pragma unroll
    for (int i = 0; i < 2; i++) af[i] = *(const short8*)&As[wr * 32 + i * 16 + lm][lq * 8];
#pragma unroll
    for (int j = 0; j < 4; j++) bf[j] = *(const short8*)&Bs[wc * 64 + j * 16 + lm][lq * 8];
#pragma unroll
    for (int i = 0; i < 2; i++)
#pragma unroll
      for (int j = 0; j < 4; j++)
        acc[i][j] = __builtin_amdgcn_mfma_f32_16x16x32_bf16(af[i], bf[j], acc[i][j], 0, 0, 0);
  }
  const bool toC1 = (col0 >= split_col);
#pragma unroll
  for (int i = 0; i < 2; i++) {
#pragma unroll
    for (int j = 0; j < 4; j++) {
      int col = col0 - (toC1 ? split_col : 0) + wc * 64 + j * 16 + lm;
#pragma unroll
      for (int r = 0; r < 4; r++) {
        int row = row0 + wr * 32 + i * 16 + lq * 4 + r;
        if (toC1) C1[(size_t)row * ldc + col] = f2bf(acc[i][j][r]);
        else C0[(size_t)row * ldc + col] = acc[i][j][r];
      }
    }
  }
}

// ---------------- bf16 MFMA GEMM 32x64 (down-proj, +=); 512 blocks ----------------
__global__ __launch_bounds__(256) void gemm_bf16_32(
    const u16* __restrict__ A, const u16* __restrict__ Bt,
    float* __restrict__ C, int M, int N, int K, int ldc)
{
  __shared__ u16 As[32][40];
  __shared__ u16 Bs[64][40];
  const int tid = threadIdx.x;
  const int row0 = blockIdx.y * 32, col0 = blockIdx.x * 64;
  const int wave = tid >> 6, lane = tid & 63;
  const int wr = wave >> 1, wc = wave & 1;   // wave tile: 16 rows x 32 cols
  const int lm = lane & 15, lq = lane >> 4;
  const int srB = tid >> 2, spB = (tid & 3) * 8;   // 64 rows x 32 u16
  f32x4 acc[2] = {};
  for (int k0 = 0; k0 < K; k0 += 32) {
    __syncthreads();
    if (tid < 128) {
      int srA = tid >> 2, spA = (tid & 3) * 8;     // 32 rows x 32 u16
      *(uint4*)&As[srA][spA] = *(const uint4*)(A + (size_t)(row0 + srA) * K + k0 + spA);
    }
    *(uint4*)&Bs[srB][spB] = *(const uint4*)(Bt + (size_t)(col0 + srB) * K + k0 + spB);
    __syncthreads();
    short8 af = *(const short8*)&As[wr * 16 + lm][lq * 8];
#pragma unroll
    for (int j = 0; j < 2; j++) {
      short8 bf = *(const short8*)&Bs[wc * 32 + j * 16 + lm][lq * 8];
      acc[j] = __builtin_amdgcn_mfma_f32_16x16x32_bf16(af, bf, acc[j], 0, 0, 0);
    }
  }
#pragma unroll
  for (int j = 0; j < 2; j++) {
    int col = col0 + wc * 32 + j * 16 + lm;
#pragma unroll
    for (int r = 0; r < 4; r++) {
      int row = row0 + wr * 16 + lq * 4 + r;
      C[(size_t)row * ldc + col] += acc[j][r];
    }
  }
}

// ---------------- fused causal conv+SiLU+headwise qkv (block = one row) ----------------
__global__ __launch_bounds__(256) void convqkv_kernel(
    const float* __restrict__ xm,
    const float* __restrict__ cw, const float* __restrict__ cb,
    const float* __restrict__ qw, const float* __restrict__ kw, const float* __restrict__ vw,
    float* __restrict__ xc, u16* __restrict__ q, u16* __restrict__ k, u16* __restrict__ v)
{
  int row = blockIdx.x;            // b*S+s
  int s = row & (S_LEN - 1);
  int g = threadIdx.x;             // channel group of 4
  int c0 = g * 4;
  const float* base = xm + (size_t)row * INNER_D + c0;

  float4 acc = {0.f, 0.f, 0.f, 0.f};
  float4 xm4 = {0.f, 0.f, 0.f, 0.f};
#pragma unroll
  for (int kk = 0; kk < 4; kk++) {
    int ts = s - 3 + kk;
    float4 xv = {0.f, 0.f, 0.f, 0.f};
    if (ts >= 0) xv = *(const float4*)(base + (ptrdiff_t)(kk - 3) * INNER_D);
    if (kk == 3) xm4 = xv;
    acc.x += xv.x * cw[(c0 + 0) * 4 + kk];
    acc.y += xv.y * cw[(c0 + 1) * 4 + kk];
    acc.z += xv.z * cw[(c0 + 2) * 4 + kk];
    acc.w += xv.w * cw[(c0 + 3) * 4 + kk];
  }
  acc.x += cb[c0 + 0]; acc.y += cb[c0 + 1];
  acc.z += cb[c0 + 2]; acc.w += cb[c0 + 3];
  acc.x = acc.x / (1.f + __expf(-acc.x));
  acc.y = acc.y / (1.f + __expf(-acc.y));
  acc.z = acc.z / (1.f + __expf(-acc.z));
  acc.w = acc.w / (1.f + __expf(-acc.w));
  *(float4*)(xc + (size_t)row * INNER_D + c0) = acc;

  const float* qg = qw + g * 16;
  const float* kg = kw + g * 16;
  const float* vg = vw + g * 16;
  float xcv[4] = {acc.x, acc.y, acc.z, acc.w};
  float xmv[4] = {xm4.x, xm4.y, xm4.z, xm4.w};
  ushort4 qs, ks, vs;
  u16* qp = (u16*)&qs; u16* kp = (u16*)&ks; u16* vp = (u16*)&vs;
#pragma unroll
  for (int o = 0; o < 4; o++) {
    float aq = 0.f, ak = 0.f, av = 0.f;
#pragma unroll
    for (int d = 0; d < 4; d++) {
      aq += xcv[d] * qg[o * 4 + d];
      ak += xcv[d] * kg[o * 4 + d];
      av += xmv[d] * vg[o * 4 + d];
    }
    qp[o] = f2bf(aq); kp[o] = f2bf(ak); vp[o] = f2bf(av);
  }
  size_t off = (size_t)row * INNER_D + c0;
  *(ushort4*)(q + off) = qs;
  *(ushort4*)(k + off) = ks;
  *(ushort4*)(v + off) = vs;
}

// ---------------- gates as skinny MFMA GEMM: C[2048,16] = qkv[2048,3072] @ W^T ----------------
__global__ __launch_bounds__(256) void gates_mfma_kernel(
    const u16* __restrict__ q, const u16* __restrict__ k, const u16* __restrict__ v,
    const u16* __restrict__ whi, const u16* __restrict__ wlo,
    const float* __restrict__ igb, const float* __restrict__ fgb,
    float* __restrict__ ig, float* __restrict__ fg)
{
  const int blk = blockIdx.x;      // 0..127
  const int tid = threadIdx.x;
  const int wave = tid >> 6, lane = tid & 63;
  const int lm = lane & 15, lq = lane >> 4;
  const int grow = blk * 16 + lm;
  const u16* parts[3] = {q, k, v};
  f32x4 acc = {};
#pragma unroll 4
  for (int kc = 0; kc < 24; kc++) {
    int k0 = wave * 768 + kc * 32;
    int part = k0 >> 10;
    int idx = (k0 & 1023) + lq * 8;
    S8 a, bh_, bl_;
    a.q = *(const uint4*)(parts[part] + (size_t)grow * INNER_D + idx);
    bh_.q = *(const uint4*)(whi + (size_t)lm * 3072 + k0 + lq * 8);
    bl_.q = *(const uint4*)(wlo + (size_t)lm * 3072 + k0 + lq * 8);
    acc = __builtin_amdgcn_mfma_f32_16x16x32_bf16(a.v, bh_.v, acc, 0, 0, 0);
    acc = __builtin_amdgcn_mfma_f32_16x16x32_bf16(a.v, bl_.v, acc, 0, 0, 0);
  }
  __shared__ float red[4][16][17];
#pragma unroll
  for (int r = 0; r < 4; r++) red[wave][lq * 4 + r][lm] = acc[r];
  __syncthreads();
  if (wave == 0) {
#pragma unroll
    for (int r = 0; r < 4; r++) {
      int row = lq * 4 + r;
      float sum = red[0][row][lm] + red[1][row][lm] + red[2][row][lm] + red[3][row][lm];
      int growr = blk * 16 + row;
      int b = growr >> 10, s = growr & (S_LEN - 1);
      if (lm < 8) ig[((size_t)(b * NHEAD + lm) << 10) + s] = sum + igb[lm];
      else        fg[((size_t)(b * NHEAD + (lm - 8)) << 10) + s] = sum + fgb[lm - 8];
    }
  }
}

// ---------------- per-(b,h) scans, shuffle-based ----------------
__global__ __launch_bounds__(1024) void scan_kernel(
    const float* __restrict__ ig, const float* __restrict__ fg,
    float* __restrict__ a, float* __restrict__ rm, float* __restrict__ enm)
{
  int bh = blockIdx.x;
  int t = threadIdx.x;
  int lane = t & 63, wv = t >> 6;
  __shared__ float sw[16];
  size_t o = ((size_t)bh << 10) + t;
  float f = fg[o];
  float lf = (f >= 0.f) ? -log1pf(__expf(-f)) : f - log1pf(__expf(f));
  float v = lf;
#pragma unroll
  for (int off = 1; off < 64; off <<= 1) {
    float u = __shfl_up(v, off);
    if (lane >= off) v += u;
  }
  if (lane == 63) sw[wv] = v;
  __syncthreads();
  float pre = 0.f;
  for (int w = 0; w < wv; w++) pre += sw[w];
  float cs = v + pre;
  float av = ig[o] - cs;
  a[o] = av;
  float m = av;
#pragma unroll
  for (int off = 1; off < 64; off <<= 1) {
    float u = __shfl_up(m, off);
    if (lane >= off) m = fmaxf(m, u);
  }
  __syncthreads();
  if (lane == 63) sw[wv] = m;
  __syncthreads();
  float pm = -3.4e38f;
  for (int w = 0; w < wv; w++) pm = fmaxf(pm, sw[w]);
  float rmx = fmaxf(m, pm);
  rm[o] = rmx;
  enm[o] = __expf(-(cs + rmx));
}

// ---------------- balanced split-K MFMA attention ----------------
__device__ __constant__ int c_qt[24] = {7,15,14,15, 6,13,14,12,13, 5,11,12,10,11, 4, 9,10, 8, 9, 3, 8, 2, 1, 0};
__device__ __constant__ int c_k0[24] = {0, 0, 7, 8, 0, 0, 0, 6, 7, 0, 0, 0, 5, 6, 0, 0, 0, 4, 5, 0, 0, 0, 0, 0};
__device__ __constant__ int c_k1[24] = {8, 8,15,16, 7, 7, 7,13,14, 6, 6, 6,11,12, 5, 5, 5, 9,10, 4, 4, 3, 2, 1};
__device__ __constant__ int c_md[24] = {0, 1, 2, 2, 0, 1, 1, 2, 2, 0, 1, 1, 2, 2, 0, 1, 1, 2, 2, 0, 1, 0, 0, 0};

__global__ __launch_bounds__(256) void attn_mfma_kernel(
    const u16* __restrict__ qhg, const u16* __restrict__ khg, const u16* __restrict__ vhg,
    const float* __restrict__ a_arr, const float* __restrict__ rm_arr, const float* __restrict__ enm_arr,
    const float* __restrict__ xc, const u16* __restrict__ zh,
    const float* __restrict__ skip, const float* __restrict__ onw,
    u16* __restrict__ hs, float* __restrict__ hpart, float* __restrict__ scpart)
{
  const int bh = blockIdx.x;
  const int job = blockIdx.y;
  const int qt = c_qt[job], k0t = c_k0[job], k1t = c_k1[job], mode = c_md[job];
  const int b = bh >> 3, h = bh & 7;
  const int s0 = qt * 64;
  const int tid = threadIdx.x;
  const int wave = tid >> 6, lane = tid & 63;
  const int lm = lane & 15, lq = lane >> 4;
  const size_t rowbase = (size_t)b * S_LEN;
  const int c0 = h * DHEAD;

  __shared__ u16 Ks[64 * 136];
  __shared__ u16 Vt[128 * 72];
  __shared__ u16 Ws[64 * 72];
  __shared__ float as_[64];

  short8 aq[4];
  {
    const u16* qp = qhg + (rowbase + s0 + wave * 16 + lm) * INNER_D + c0 + lq * 8;
#pragma unroll
    for (int kc = 0; kc < 4; kc++) {
      S8 tmp; tmp.q = *(const uint4*)(qp + kc * 32);
      aq[kc] = tmp.v;
    }
  }
  float rmv[4];
#pragma unroll
  for (int r = 0; r < 4; r++)
    rmv[r] = rm_arr[(size_t)bh * S_LEN + s0 + wave * 16 + lq * 4 + r];

  f32x4 accH[8] = {};
  float sc_acc[4] = {0.f, 0.f, 0.f, 0.f};
  const float scale = 0.08838834764831845f;  // 1/sqrt(128)

  for (int kt = k0t; kt < k1t; kt++) {
    const int t0 = kt * 64;
    __syncthreads();
#pragma unroll
    for (int rep = 0; rep < 4; rep++) {
      int idx = rep * 256 + tid;
      int r = idx >> 4, seg = (idx & 15) * 8;
      *(uint4*)&Ks[r * 136 + seg] =
          *(const uint4*)(khg + (rowbase + t0 + r) * INNER_D + c0 + seg);
    }
#pragma unroll
    for (int rep = 0; rep < 4; rep++) {
      int idx = rep * 256 + tid;
      int t = idx & 63, dgrp = idx >> 6;
      S8 vv;
      vv.q = *(const uint4*)(vhg + (rowbase + t0 + t) * INNER_D + c0 + dgrp * 8);
#pragma unroll
      for (int j = 0; j < 8; j++) Vt[(dgrp * 8 + j) * 72 + t] = vv.u[j];
    }
    if (tid < 64) as_[tid] = a_arr[(size_t)bh * S_LEN + t0 + tid];
    __syncthreads();

    f32x4 pacc[4] = {};
#pragma unroll
    for (int kc = 0; kc < 4; kc++) {
#pragma unroll
      for (int cb = 0; cb < 4; cb++) {
        short8 bk = *(const short8*)&Ks[(cb * 16 + lm) * 136 + kc * 32 + lq * 8];
        pacc[cb] = __builtin_amdgcn_mfma_f32_16x16x32_bf16(aq[kc], bk, pacc[cb], 0, 0, 0);
      }
    }

    float wpart[4] = {0.f, 0.f, 0.f, 0.f};
#pragma unroll
    for (int cb = 0; cb < 4; cb++) {
      int colg = t0 + cb * 16 + lm;
      float ea = as_[cb * 16 + lm];
#pragma unroll
      for (int r = 0; r < 4; r++) {
        int rowg = s0 + wave * 16 + lq * 4 + r;
        float wv = pacc[cb][r] * scale * __expf(ea - rmv[r]);
        if (colg > rowg) wv = 0.f;
        wpart[r] += wv;
        Ws[(wave * 16 + lq * 4 + r) * 72 + cb * 16 + lm] = f2bf(wv);
      }
    }
#pragma unroll
    for (int r = 0; r < 4; r++) {
      float sr = wpart[r];
      sr += __shfl_xor(sr, 1); sr += __shfl_xor(sr, 2);
      sr += __shfl_xor(sr, 4); sr += __shfl_xor(sr, 8);
      sc_acc[r] += sr;
    }

#pragma unroll
    for (int kc = 0; kc < 2; kc++) {
      short8 aw = *(const short8*)&Ws[(wave * 16 + lm) * 72 + kc * 32 + lq * 8];
#pragma unroll
      for (int nb = 0; nb < 8; nb++) {
        short8 bv = *(const short8*)&Vt[(nb * 16 + lm) * 72 + kc * 32 + lq * 8];
        accH[nb] = __builtin_amdgcn_mfma_f32_16x16x32_bf16(aw, bv, accH[nb], 0, 0, 0);
      }
    }
  }

  if (mode != 0) {
    int slot = mode - 1;
    int qr = qt - 8;
    float* Hp = hpart + (((size_t)slot * 16 + bh) * 8 + qr) * 8192;
    float* sp = scpart + ((slot * 16 + bh) * 8 + qr) * 64;
#pragma unroll
    for (int r = 0; r < 4; r++) {
      int row = wave * 16 + lq * 4 + r;
      if (lm == 0) sp[row] = sc_acc[r];
#pragma unroll
      for (int nb = 0; nb < 8; nb++)
        Hp[row * 128 + nb * 16 + lm] = accH[nb][r];
    }
    return;
  }

  float inv[4], muv[4], rsv[4];
#pragma unroll
  for (int r = 0; r < 4; r++) {
    int rowg = s0 + wave * 16 + lq * 4 + r;
    float nrm = fmaxf(fabsf(sc_acc[r]), enm_arr[(size_t)bh * S_LEN + rowg]);
    inv[r] = 1.f / (nrm + 1e-6f);
  }
#pragma unroll
  for (int r = 0; r < 4; r++) {
    float s = 0.f, qq = 0.f;
#pragma unroll
    for (int nb = 0; nb < 8; nb++) {
      float hv = accH[nb][r] * inv[r];
      accH[nb][r] = hv;
      s += hv; qq += hv * hv;
    }
    s += __shfl_xor(s, 1); s += __shfl_xor(s, 2); s += __shfl_xor(s, 4); s += __shfl_xor(s, 8);
    qq += __shfl_xor(qq, 1); qq += __shfl_xor(qq, 2); qq += __shfl_xor(qq, 4); qq += __shfl_xor(qq, 8);
    float mu = s * (1.f / DHEAD);
    float var = qq * (1.f / DHEAD) - mu * mu;
    muv[r] = mu;
    rsv[r] = rsqrtf(var + 1e-5f);
  }
  float ow[8], sk[8];
#pragma unroll
  for (int nb = 0; nb < 8; nb++) {
    ow[nb] = onw[c0 + nb * 16 + lm];
    sk[nb] = skip[c0 + nb * 16 + lm];
  }
#pragma unroll
  for (int r = 0; r < 4; r++) {
    int rowg = s0 + wave * 16 + lq * 4 + r;
    size_t base = (rowbase + rowg) * INNER_D + c0;
#pragma unroll
    for (int nb = 0; nb < 8; nb++) {
      int d = nb * 16 + lm;
      float xcv = xc[base + d];
      float zv = bf2f(zh[base + d]);
      float hn = (accH[nb][r] - muv[r]) * rsv[r] * ow[nb] + sk[nb] * xcv;
      float o = hn * (zv / (1.f + __expf(-zv)));
      hs[base + d] = f2bf(o);
    }
  }
}

// combine two partial slots for rows s >= 512; one wave per row.
__global__ __launch_bounds__(256) void attn_combine_kernel(
    const float* __restrict__ hpart, const float* __restrict__ scpart,
    const float* __restrict__ enm,
    const float* __restrict__ xc, const u16* __restrict__ zh,
    const float* __restrict__ skip, const float* __restrict__ onw,
    u16* __restrict__ hs)
{
  int wave = threadIdx.x >> 6, lane = threadIdx.x & 63;
  int gid = blockIdx.x * 4 + wave;
  int bh = gid >> 9;
  int rr = gid & 511;
  int qr = rr >> 6, row = rr & 63;
  int b = bh >> 3, hh = bh & 7;
  int s = (qr + 8) * 64 + row;
  size_t off = (((size_t)bh) * 8 + qr) * 8192 + row * 128 + lane * 2;
  float2 h0 = *(const float2*)(hpart + off);
  float2 h1 = *(const float2*)(hpart + 1048576 + off);
  int sidx = (bh * 8 + qr) * 64 + row;
  float sc = scpart[sidx] + scpart[8192 + sidx];
  float nrm = fmaxf(fabsf(sc), enm[(size_t)bh * S_LEN + s]);
  float inv = 1.f / (nrm + 1e-6f);
  float hx = (h0.x + h1.x) * inv, hy = (h0.y + h1.y) * inv;
  float sm = hx + hy, sq = hx * hx + hy * hy;
#pragma unroll
  for (int off2 = 32; off2; off2 >>= 1) { sm += __shfl_xor(sm, off2); sq += __shfl_xor(sq, off2); }
  float mu = sm * (1.f / DHEAD);
  float var = sq * (1.f / DHEAD) - mu * mu;
  float rs = rsqrtf(var + 1e-5f);
  int c0 = hh * DHEAD + lane * 2;
  size_t base = ((size_t)(b * S_LEN + s)) * INNER_D + c0;
  float2 xc2 = *(const float2*)(xc + base);
  ushort2 z2u = *(const ushort2*)(zh + base);
  float z2x = bf2f(z2u.x), z2y = bf2f(z2u.y);
  float skx = skip[c0], sky = skip[c0 + 1];
  float owx = onw[c0],  owy = onw[c0 + 1];
  ushort2 o;
  o.x = f2bf(((hx - mu) * rs * owx + skx * xc2.x) * (z2x / (1.f + __expf(-z2x))));
  o.y = f2bf(((hy - mu) * rs * owy + sky * xc2.y) * (z2y / (1.f + __expf(-z2y))));
  *(ushort2*)(hs + base) = o;
}

// ---------------- head ----------------
__global__ __launch_bounds__(64) void head_kernel(
    const float* __restrict__ ln96, const float* __restrict__ hW, const float* __restrict__ hb,
    float* __restrict__ out)
{
  int row = blockIdx.x;
  int n = threadIdx.x;
  if (n >= 21) return;
  float acc = hb[n];
  const float* xr = ln96 + (size_t)row * E_DIM;
  for (int kk = 0; kk < E_DIM; kk++) acc += xr[kk] * hW[kk * 21 + n];
  out[row * 21 + n] = acc;
}

extern "C" void kernel_launch(void* const* d_in, const int* in_sizes, int n_in,
                              void* d_out, int out_size, void* d_ws, size_t ws_size,
                              hipStream_t stream)
{
  const float* x_enc   = (const float*)d_in[0];
  const float* x_mark  = (const float*)d_in[1];
  const float* emb_W   = (const float*)d_in[4];
  const float* emb_b   = (const float*)d_in[5];
  const float* ln_w    = (const float*)d_in[6];
  const float* up_W    = (const float*)d_in[7];
  const float* conv_W  = (const float*)d_in[8];
  const float* conv_b  = (const float*)d_in[9];
  const float* q_W     = (const float*)d_in[10];
  const float* k_W     = (const float*)d_in[11];
  const float* v_W     = (const float*)d_in[12];
  const float* ig_W    = (const float*)d_in[13];
  const float* ig_b    = (const float*)d_in[14];
  const float* fg_W    = (const float*)d_in[15];
  const float* fg_b    = (const float*)d_in[16];
  const float* skip_w  = (const float*)d_in[17];
  const float* onorm_w = (const float*)d_in[18];
  const float* down_W  = (const float*)d_in[19];
  const float* post_ln = (const float*)d_in[20];
  const float* head_W  = (const float*)d_in[21];
  const float* head_b  = (const float*)d_in[22];

  float* p = (float*)d_ws;
  float* x    = p; p += 1048576;   // 2048*512 f32
  float* xm   = p; p += 2097152;   // 2048*1024 f32; reused as hsbh bf16 after convqkv
  float* xc   = p; p += 2097152;
  float* igb_ = p; p += 16384;
  float* fgb_ = p; p += 16384;
  float* ab   = p; p += 16384;
  float* rmb  = p; p += 16384;
  float* enmb = p; p += 16384;
  float* ln96 = p; p += 98304;
  u16* qhb = (u16*)p; p += 1048576;  // 2048*1024 u16
  u16* khb = (u16*)p; p += 1048576;
  u16* vhb = (u16*)p; p += 1048576;
  u16* zh  = (u16*)p; p += 524288;   // 2048*1024 u16
  u16* xnh = (u16*)p; p += 524288;   // 2048*512 u16
  u16* upWtA = (u16*)p; p += 2097152; // 4 x 2048x512 u16
  u16* dnWtA = (u16*)p; p += 1048576; // 4 x 512x1024 u16
  u16* gtwH = (u16*)p; p += 98304;    // 4 x 16 x 3072 u16
  u16* gtwL = (u16*)p; p += 98304;
  float* hpart = p; p += 2097152;     // 2 x 16 x 8 x 64 x 128 f32
  float* scpart = p; p += 16384;
  u16* hsbh = (u16*)xm;
  // total ~15.3M floats = 61 MB

  embed_kernel<<<2048, 128, 0, stream>>>(x_enc, x_mark, emb_W, emb_b, x);
  transpose_bf16_all_kernel<<<dim3(8, 32, 4), 256, 0, stream>>>(up_W, upWtA, 512, 2048);
  transpose_bf16_all_kernel<<<dim3(16, 8, 4), 256, 0, stream>>>(down_W, dnWtA, 1024, 512);
  gates_w_transpose_kernel<<<dim3(12, 16, 4), 256, 0, stream>>>(ig_W, fg_W, gtwH, gtwL);

  for (int L = 0; L < 4; L++) {
    ln_kernel<<<2048, 256, 0, stream>>>(x, ln_w + L * 512, xnh);
    gemm_bf16_split64<<<dim3(16, 32), 256, 0, stream>>>(
        xnh, upWtA + (size_t)L * 1048576, xm, zh, 2048, 2048, 512, 1024, 1024);
    convqkv_kernel<<<2048, 256, 0, stream>>>(
        xm, conv_W + L * 4096, conv_b + L * 1024,
        q_W + L * 4096, k_W + L * 4096, v_W + L * 4096,
        xc, qhb, khb, vhb);
    gates_mfma_kernel<<<128, 256, 0, stream>>>(
        qhb, khb, vhb, gtwH + (size_t)L * 49152, gtwL + (size_t)L * 49152,
        ig_b + L * 8, fg_b + L * 8, igb_, fgb_);
    scan_kernel<<<16, 1024, 0, stream>>>(igb_, fgb_, ab, rmb, enmb);
    attn_mfma_kernel<<<dim3(16, 24), 256, 0, stream>>>(
        qhb, khb, vhb, ab, rmb, enmb, xc, zh,
        skip_w + L * 1024, onorm_w + L * 1024, hsbh, hpart, scpart);
    attn_combine_kernel<<<2048, 256, 0, stream>>>(
        hpart, scpart, enmb, xc, zh, skip_w + L * 1024, onorm_w + L * 1024, hsbh);
    gemm_bf16_32<<<dim3(8, 64), 256, 0, stream>>>(
        hsbh, dnWtA + (size_t)L * 524288, x, 2048, 512, 1024, 512);
  }

  ln_final_kernel<<<192, 256, 0, stream>>>(x, post_ln, ln96);
  head_kernel<<<192, 64, 0, stream>>>(ln96, head_W, head_b, (float*)d_out);
}